// Round 1
// baseline (10763.927 us; speedup 1.0000x reference)
//
#include <hip/hip_runtime.h>
#include <math.h>

#define N_NODES 20000
#define N_EDGES 400000
#define NH 10

// ---------------------------------------------------------------- helpers
__device__ __forceinline__ float gelu_f(float x) {
    float x3 = x * x * x;
    return 0.5f * x * (1.0f + tanhf(0.7978845608028654f * (x + 0.044715f * x3)));
}
__device__ __forceinline__ float elu_f(float x) {
    return x > 0.0f ? x : (expf(x) - 1.0f);
}

// ---------------------------------------------------------------- GEMM
// C[M,N] = act(A[M,K] @ W[K,N] + bias[N]); act: 0=none, 1=elu
template<int ACT>
__global__ __launch_bounds__(256) void gemm_kernel(
    const float* __restrict__ A, const float* __restrict__ W,
    const float* __restrict__ bias, float* __restrict__ C,
    int M, int N, int K)
{
    __shared__ float As[16][68];
    __shared__ float Bs[16][68];
    const int tid = threadIdx.x;
    const int m0 = blockIdx.y * 64;
    const int n0 = blockIdx.x * 64;
    const int tr = tid >> 4;           // 0..15
    const int tc = tid & 15;           // 0..15
    const int arow = tid >> 2;         // 0..63
    const int acol = (tid & 3) << 2;   // 0,4,8,12
    const int brow = tid >> 4;         // 0..15
    const int bcol = (tid & 15) << 2;  // 0..60
    const bool nvec = ((N & 3) == 0);

    float acc[4][4] = {};
    for (int k0 = 0; k0 < K; k0 += 16) {
        // A tile: 64 rows x 16 k (K is always a multiple of 16 here)
        {
            int m = m0 + arow;
            float4 v = make_float4(0.f, 0.f, 0.f, 0.f);
            if (m < M) v = *reinterpret_cast<const float4*>(A + (size_t)m * K + k0 + acol);
            As[acol + 0][arow] = v.x; As[acol + 1][arow] = v.y;
            As[acol + 2][arow] = v.z; As[acol + 3][arow] = v.w;
        }
        // B tile: 16 k x 64 n
        {
            int k = k0 + brow;
            const float* bp = W + (size_t)k * N + n0 + bcol;
            if (nvec && (n0 + bcol + 4 <= N)) {
                float4 v = *reinterpret_cast<const float4*>(bp);
                Bs[brow][bcol + 0] = v.x; Bs[brow][bcol + 1] = v.y;
                Bs[brow][bcol + 2] = v.z; Bs[brow][bcol + 3] = v.w;
            } else {
                #pragma unroll
                for (int j = 0; j < 4; ++j)
                    Bs[brow][bcol + j] = (n0 + bcol + j < N) ? bp[j] : 0.f;
            }
        }
        __syncthreads();
        #pragma unroll
        for (int kk = 0; kk < 16; ++kk) {
            float a[4], b[4];
            #pragma unroll
            for (int i = 0; i < 4; ++i) a[i] = As[kk][tr * 4 + i];
            #pragma unroll
            for (int j = 0; j < 4; ++j) b[j] = Bs[kk][tc * 4 + j];
            #pragma unroll
            for (int i = 0; i < 4; ++i)
                #pragma unroll
                for (int j = 0; j < 4; ++j)
                    acc[i][j] = fmaf(a[i], b[j], acc[i][j]);
        }
        __syncthreads();
    }
    #pragma unroll
    for (int i = 0; i < 4; ++i) {
        int m = m0 + tr * 4 + i;
        if (m >= M) continue;
        #pragma unroll
        for (int j = 0; j < 4; ++j) {
            int n = n0 + tc * 4 + j;
            if (n >= N) continue;
            float v = acc[i][j] + bias[n];
            if (ACT == 1) v = elu_f(v);
            C[(size_t)m * N + n] = v;
        }
    }
}

// ---------------------------------------------------------------- relation transform
// Y[n,h,e] = sum_d X[n,h,d] * R[h,d,e]   (R already offset to the relation)
__global__ void relt_kernel(const float* __restrict__ X, const float* __restrict__ R,
                            float* __restrict__ Y, int total, int D)
{
    int tid = blockIdx.x * blockDim.x + threadIdx.x;
    if (tid >= total) return;
    int dout = tid % D;
    int nh = tid / D;          // n*NH + h
    int h = nh % NH;
    const float* x = X + (size_t)nh * D;
    const float* r = R + (size_t)h * D * D + dout;
    float acc = 0.f;
    for (int d = 0; d < D; ++d) acc = fmaf(x[d], r[(size_t)d * D], acc);
    Y[tid] = acc;
}

// ---------------------------------------------------------------- elementwise gelu
__global__ void gelu_kernel(const float* __restrict__ X, float* __restrict__ Y, int total)
{
    int tid = blockIdx.x * blockDim.x + threadIdx.x;
    if (tid < total) Y[tid] = gelu_f(X[tid]);
}

// ---------------------------------------------------------------- edge logits
// logit[e,h] = (q[dst,h,:] . kr[src,h,:]) * scale * prel[h] + ea[e]*ew[h] + eb[h]
__global__ void logit_kernel(const float* __restrict__ Q, const float* __restrict__ KR,
                             const int* __restrict__ ei, const float* __restrict__ ea,
                             const float* __restrict__ prel, const float* __restrict__ ew,
                             const float* __restrict__ eb, float* __restrict__ logit,
                             int D, float scale)
{
    int tid = blockIdx.x * blockDim.x + threadIdx.x;
    if (tid >= N_EDGES * NH) return;
    int e = tid / NH, h = tid - e * NH;
    int src = ei[e], dst = ei[N_EDGES + e];
    const float* q = Q + ((size_t)dst * NH + h) * D;
    const float* k = KR + ((size_t)src * NH + h) * D;
    float acc = 0.f;
    for (int d = 0; d < D; ++d) acc = fmaf(q[d], k[d], acc);
    logit[tid] = acc * scale * prel[h] + ea[e] * ew[h] + eb[h];
}

// ---------------------------------------------------------------- segment softmax (CSR, in-place)
__global__ void softmax_kernel(float* __restrict__ logit, const int* __restrict__ rp,
                               const int* __restrict__ eid, float* __restrict__ sb)
{
    int tid = blockIdx.x * blockDim.x + threadIdx.x;
    if (tid >= N_NODES * NH) return;
    int dst = tid / NH, h = tid - dst * NH;
    int s0 = rp[dst], s1 = rp[dst + 1];
    float m = -3.4e38f;
    for (int p = s0; p < s1; ++p) m = fmaxf(m, logit[eid[p] * NH + h]);
    float s = 0.f;
    for (int p = s0; p < s1; ++p) {
        int idx = eid[p] * NH + h;
        float w = expf(logit[idx] - m);
        s += w;
        logit[idx] = w;
    }
    sb[tid] = s;
}

// ---------------------------------------------------------------- CSR aggregation
// out[dst,h*D+d] = (1/(s+eps)) * sum_p w[eid[p],h] * vr[src[p], h*D+d]
__global__ void agg_kernel(const float* __restrict__ W, const float* __restrict__ VR,
                           const int* __restrict__ rp, const int* __restrict__ srcA,
                           const int* __restrict__ eid, const float* __restrict__ sb,
                           float* __restrict__ out, int D)
{
    int dst = blockIdx.x;
    int HD = NH * D;
    int s0 = rp[dst], s1 = rp[dst + 1];
    for (int o = threadIdx.x; o < HD; o += blockDim.x) {
        int h = o / D;
        float acc = 0.f;
        for (int p = s0; p < s1; ++p)
            acc = fmaf(W[eid[p] * NH + h], VR[(size_t)srcA[p] * HD + o], acc);
        out[(size_t)dst * HD + o] = acc / (sb[dst * NH + h] + 1e-16f);
    }
}

// ---------------------------------------------------------------- CSR build
__global__ void count_kernel(const int* __restrict__ ei, int* __restrict__ cnt)
{
    int e = blockIdx.x * blockDim.x + threadIdx.x;
    if (e < N_EDGES) atomicAdd(&cnt[ei[N_EDGES + e]], 1);
}

__global__ void scatter_kernel(const int* __restrict__ ei, int* __restrict__ cursor,
                               int* __restrict__ srcA, int* __restrict__ eidA)
{
    int e = blockIdx.x * blockDim.x + threadIdx.x;
    if (e >= N_EDGES) return;
    int dst = ei[N_EDGES + e];
    int pos = atomicAdd(&cursor[dst], 1);
    srcA[pos] = ei[e];
    eidA[pos] = e;
}

// single-block exclusive scan of n ints -> rp[0..n], also copies to cursor
__global__ void exscan_kernel(const int* __restrict__ cnt, int* __restrict__ rp,
                              int* __restrict__ cursor, int n)
{
    __shared__ int buf[1024];
    __shared__ int carry;
    int t = threadIdx.x;
    if (t == 0) carry = 0;
    __syncthreads();
    for (int base = 0; base < n; base += 1024) {
        int v = (base + t < n) ? cnt[base + t] : 0;
        buf[t] = v;
        __syncthreads();
        for (int off = 1; off < 1024; off <<= 1) {
            int x = (t >= off) ? buf[t - off] : 0;
            __syncthreads();
            buf[t] += x;
            __syncthreads();
        }
        int excl = buf[t] - v + carry;
        if (base + t < n) { rp[base + t] = excl; cursor[base + t] = excl; }
        int total = buf[1023];
        __syncthreads();
        if (t == 0) carry += total;
        __syncthreads();
    }
    if (t == 0) rp[n] = carry;
}

// ---------------------------------------------------------------- batchnorm
__global__ void colstat_kernel(const float* __restrict__ X, float* __restrict__ sums,
                               int M, int N)
{
    __shared__ float ls[256], lq[256];
    int c = blockIdx.x * 64 + (threadIdx.x & 63);
    int rl = threadIdx.x >> 6;
    float s = 0.f, q = 0.f;
    for (int r = blockIdx.y * 4 + rl; r < M; r += gridDim.y * 4) {
        float v = X[(size_t)r * N + c];
        s += v; q = fmaf(v, v, q);
    }
    ls[threadIdx.x] = s; lq[threadIdx.x] = q;
    __syncthreads();
    if (rl == 0) {
        s = ls[threadIdx.x] + ls[threadIdx.x + 64] + ls[threadIdx.x + 128] + ls[threadIdx.x + 192];
        q = lq[threadIdx.x] + lq[threadIdx.x + 64] + lq[threadIdx.x + 128] + lq[threadIdx.x + 192];
        atomicAdd(&sums[c], s);
        atomicAdd(&sums[N + c], q);
    }
}

__global__ void bn_kernel(float* __restrict__ X, const float* __restrict__ sums,
                          const float* __restrict__ g, const float* __restrict__ b,
                          int M, int N)
{
    int tid = blockIdx.x * blockDim.x + threadIdx.x;
    if (tid >= M * N) return;
    int c = tid % N;
    float mu = sums[c] / (float)M;
    float var = sums[N + c] / (float)M - mu * mu;
    X[tid] = (X[tid] - mu) * rsqrtf(var + 1e-5f) * g[c] + b[c];
}

// ---------------------------------------------------------------- output epilogues
__global__ void rownorm_kernel(const float* __restrict__ X, float* __restrict__ out)
{
    int row = blockIdx.x;
    int l = threadIdx.x;   // 64 threads
    const float* x = X + (size_t)row * 128;
    float v0 = x[l], v1 = x[l + 64];
    float ss = v0 * v0 + v1 * v1;
    #pragma unroll
    for (int off = 32; off; off >>= 1) ss += __shfl_xor(ss, off);
    float inv = rsqrtf(ss + 1e-12f);
    out[(size_t)row * 128 + l] = v0 * inv;
    out[(size_t)row * 128 + l + 64] = v1 * inv;
}

__global__ void rowsoftmax_kernel(const float* __restrict__ X, float* __restrict__ out)
{
    int row = blockIdx.x;
    int l = threadIdx.x;   // 64 threads, 129 columns
    const float* x = X + (size_t)row * 129;
    float v0 = x[l], v1 = x[l + 64];
    float v2 = (l == 0) ? x[128] : -3.4e38f;
    float m = fmaxf(fmaxf(v0, v1), v2);
    #pragma unroll
    for (int off = 32; off; off >>= 1) m = fmaxf(m, __shfl_xor(m, off));
    float e0 = expf(v0 - m), e1 = expf(v1 - m);
    float e2 = (l == 0) ? expf(v2 - m) : 0.f;
    float s = e0 + e1 + e2;
    #pragma unroll
    for (int off = 32; off; off >>= 1) s += __shfl_xor(s, off);
    float inv = 1.f / s;
    out[(size_t)row * 129 + l] = e0 * inv;
    out[(size_t)row * 129 + l + 64] = e1 * inv;
    if (l == 0) out[(size_t)row * 129 + 128] = e2 * inv;
}

// ---------------------------------------------------------------- host-side plumbing
static inline void launch_gemm(const float* A, const float* W, const float* bias, float* C,
                               int M, int N, int K, int act, hipStream_t s)
{
    dim3 grid((N + 63) / 64, (M + 63) / 64);
    if (act) gemm_kernel<1><<<grid, 256, 0, s>>>(A, W, bias, C, M, N, K);
    else     gemm_kernel<0><<<grid, 256, 0, s>>>(A, W, bias, C, M, N, K);
}

struct LayerParams {
    const float *kw, *kb, *qw, *qb, *vw, *vb, *arel, *mrel, *prel, *ew, *eb, *alw, *alb;
};

struct CsrRel { const int* rp; const int* src; const int* eid; };

static void run_layer(const LayerParams& P, int fin, int D,
                      const float* xa, const float* xu,
                      float* B2, float* B3, float* B4, float* B5, float* B6, float* B7,
                      float* ya, float* yu,
                      const int* ei_au, const int* ei_ua,
                      const float* ea_au, const float* ea_ua,
                      const CsrRel& au, const CsrRel& ua,
                      float* LOGIT, float* SB, hipStream_t s)
{
    const int HD = NH * D;
    const float scale = 1.0f / sqrtf((float)D);
    const int nhd = N_NODES * HD;
    const int gEW = (N_EDGES * NH + 255) / 256;
    const int gNH = (N_NODES * NH + 255) / 256;
    const int gNHD = (nhd + 255) / 256;

    // ---- relation ant->user (r=0): k/v from ant, q from user
    launch_gemm(xa, P.kw, P.kb, B2, N_NODES, HD, fin, 0, s);                       // k_a
    relt_kernel<<<gNHD, 256, 0, s>>>(B2, P.arel, B3, nhd, D);                      // kr_a
    launch_gemm(xa, P.vw, P.vb, B2, N_NODES, HD, fin, 0, s);                       // v_a
    relt_kernel<<<gNHD, 256, 0, s>>>(B2, P.mrel, B4, nhd, D);                      // vr_a
    launch_gemm(xu, P.qw + (size_t)fin * HD, P.qb + HD, B5, N_NODES, HD, fin, 0, s); // q_u
    logit_kernel<<<gEW, 256, 0, s>>>(B5, B3, ei_au, ea_au, P.prel, P.ew, P.eb,
                                     LOGIT, D, scale);
    softmax_kernel<<<gNH, 256, 0, s>>>(LOGIT, au.rp, au.eid, SB);
    agg_kernel<<<N_NODES, 256, 0, s>>>(LOGIT, B4, au.rp, au.src, au.eid, SB, B6, D); // agg_u

    // ---- relation user->ant (r=1): k/v from user, q from ant
    launch_gemm(xu, P.kw + (size_t)fin * HD, P.kb + HD, B2, N_NODES, HD, fin, 0, s); // k_u
    relt_kernel<<<gNHD, 256, 0, s>>>(B2, P.arel + (size_t)NH * D * D, B3, nhd, D);   // kr_u
    launch_gemm(xu, P.vw + (size_t)fin * HD, P.vb + HD, B2, N_NODES, HD, fin, 0, s); // v_u
    relt_kernel<<<gNHD, 256, 0, s>>>(B2, P.mrel + (size_t)NH * D * D, B4, nhd, D);   // vr_u
    launch_gemm(xa, P.qw, P.qb, B5, N_NODES, HD, fin, 0, s);                          // q_a
    logit_kernel<<<gEW, 256, 0, s>>>(B5, B3, ei_ua, ea_ua, P.prel + NH, P.ew + NH,
                                     P.eb + NH, LOGIT, D, scale);
    softmax_kernel<<<gNH, 256, 0, s>>>(LOGIT, ua.rp, ua.eid, SB);
    agg_kernel<<<N_NODES, 256, 0, s>>>(LOGIT, B4, ua.rp, ua.src, ua.eid, SB, B7, D); // agg_a

    // ---- per-type output linear with gelu-in, elu-out
    gelu_kernel<<<gNHD, 256, 0, s>>>(B7, B2, nhd);
    launch_gemm(B2, P.alw, P.alb, ya, N_NODES, HD, HD, 1, s);                         // out_a
    gelu_kernel<<<gNHD, 256, 0, s>>>(B6, B2, nhd);
    launch_gemm(B2, P.alw + (size_t)HD * HD, P.alb + HD, yu, N_NODES, HD, HD, 1, s);  // out_u
}

extern "C" void kernel_launch(void* const* d_in, const int* in_sizes, int n_in,
                              void* d_out, int out_size, void* d_ws, size_t ws_size,
                              hipStream_t stream)
{
    // ---- inputs
    const float* x_ant  = (const float*)d_in[0];
    const float* x_user = (const float*)d_in[1];
    const float* ea_au  = (const float*)d_in[2];
    const float* ea_ua  = (const float*)d_in[3];
    LayerParams L1 = {
        (const float*)d_in[4],  (const float*)d_in[5],  (const float*)d_in[6],
        (const float*)d_in[7],  (const float*)d_in[8],  (const float*)d_in[9],
        (const float*)d_in[10], (const float*)d_in[11], (const float*)d_in[12],
        (const float*)d_in[13], (const float*)d_in[14], (const float*)d_in[15],
        (const float*)d_in[16]
    };
    LayerParams L2 = {
        (const float*)d_in[17], (const float*)d_in[18], (const float*)d_in[19],
        (const float*)d_in[20], (const float*)d_in[21], (const float*)d_in[22],
        (const float*)d_in[23], (const float*)d_in[24], (const float*)d_in[25],
        (const float*)d_in[26], (const float*)d_in[27], (const float*)d_in[28],
        (const float*)d_in[29]
    };
    const float* lin1_w  = (const float*)d_in[30];
    const float* lin1_b  = (const float*)d_in[31];
    const float* bn_g    = (const float*)d_in[32];
    const float* bn_b    = (const float*)d_in[33];
    const float* lin2_wa = (const float*)d_in[34];
    const float* lin2_ba = (const float*)d_in[35];
    const float* lin2_wu = (const float*)d_in[36];
    const float* lin2_bu = (const float*)d_in[37];
    const int*   ei_au   = (const int*)d_in[38];
    const int*   ei_ua   = (const int*)d_in[39];

    // ---- workspace arena (floats)
    float* F = (float*)d_ws;
    const size_t SLOT = (size_t)N_NODES * 320;
    float* B0 = F + 0 * SLOT;
    float* B1 = F + 1 * SLOT;
    float* B2 = F + 2 * SLOT;
    float* B3 = F + 3 * SLOT;
    float* B4 = F + 4 * SLOT;
    float* B5 = F + 5 * SLOT;
    float* B6 = F + 6 * SLOT;
    float* B7 = F + 7 * SLOT;
    float* LOGIT = F + 8 * SLOT;                       // E*NH
    float* SB    = LOGIT + (size_t)N_EDGES * NH;       // N*NH
    float* STATS = SB + (size_t)N_NODES * NH;          // 1024 (sum512 + sumsq512)
    int* I = (int*)(STATS + 1024);
    int* rp_au  = I;
    int* rp_ua  = rp_au + N_NODES + 1;
    int* src_au = rp_ua + N_NODES + 1;
    int* eid_au = src_au + N_EDGES;
    int* src_ua = eid_au + N_EDGES;
    int* eid_ua = src_ua + N_EDGES;
    int* cursor = eid_ua + N_EDGES;
    int* counts = cursor + N_NODES;

    const int gE = (N_EDGES + 255) / 256;

    // ---- CSR build (per relation, reused by both layers)
    hipMemsetAsync(counts, 0, N_NODES * sizeof(int), stream);
    count_kernel<<<gE, 256, 0, stream>>>(ei_au, counts);
    exscan_kernel<<<1, 1024, 0, stream>>>(counts, rp_au, cursor, N_NODES);
    scatter_kernel<<<gE, 256, 0, stream>>>(ei_au, cursor, src_au, eid_au);

    hipMemsetAsync(counts, 0, N_NODES * sizeof(int), stream);
    count_kernel<<<gE, 256, 0, stream>>>(ei_ua, counts);
    exscan_kernel<<<1, 1024, 0, stream>>>(counts, rp_ua, cursor, N_NODES);
    scatter_kernel<<<gE, 256, 0, stream>>>(ei_ua, cursor, src_ua, eid_ua);

    CsrRel au = { rp_au, src_au, eid_au };
    CsrRel ua = { rp_ua, src_ua, eid_ua };

    // ---- HGT layer 1: fin=128, D=16 -> outputs [N,160] in B0 (ant), B1 (user), elu applied
    run_layer(L1, 128, 16, x_ant, x_user, B2, B3, B4, B5, B6, B7, B0, B1,
              ei_au, ei_ua, ea_au, ea_ua, au, ua, LOGIT, SB, stream);

    // ---- HGT layer 2: fin=160, D=32 -> outputs [N,320] in B0, B1, elu applied
    run_layer(L2, 160, 32, B0, B1, B2, B3, B4, B5, B6, B7, B0, B1,
              ei_au, ei_ua, ea_au, ea_ua, au, ua, LOGIT, SB, stream);

    // ---- lin1 + elu:  [N,320] @ [320,512]
    float* L1A = B2;   // spans B2..B3 (N*512 floats)
    float* L1U = B4;   // spans B4..B5
    launch_gemm(B0, lin1_w, lin1_b, L1A, N_NODES, 512, 320, 1, stream);
    launch_gemm(B1, lin1_w + (size_t)320 * 512, lin1_b + 512, L1U, N_NODES, 512, 320, 1, stream);

    // ---- batchnorm (population stats over rows), in-place
    hipMemsetAsync(STATS, 0, 1024 * sizeof(float), stream);
    colstat_kernel<<<dim3(8, 32), 256, 0, stream>>>(L1A, STATS, N_NODES, 512);
    bn_kernel<<<(N_NODES * 512 + 255) / 256, 256, 0, stream>>>(L1A, STATS, bn_g, bn_b,
                                                               N_NODES, 512);
    hipMemsetAsync(STATS, 0, 1024 * sizeof(float), stream);
    colstat_kernel<<<dim3(8, 32), 256, 0, stream>>>(L1U, STATS, N_NODES, 512);
    bn_kernel<<<(N_NODES * 512 + 255) / 256, 256, 0, stream>>>(L1U, STATS, bn_g + 512,
                                                               bn_b + 512, N_NODES, 512);

    // ---- lin2 + output epilogues
    float* OUTA = B6;  // [N,128]
    float* OUTU = B7;  // [N,129]
    launch_gemm(L1A, lin2_wa, lin2_ba, OUTA, N_NODES, 128, 512, 0, stream);
    rownorm_kernel<<<N_NODES, 64, 0, stream>>>(OUTA, (float*)d_out);
    launch_gemm(L1U, lin2_wu, lin2_bu, OUTU, N_NODES, 129, 512, 0, stream);
    rowsoftmax_kernel<<<N_NODES, 64, 0, stream>>>(
        OUTU, (float*)d_out + (size_t)N_NODES * 128);
}

// Round 3
// 2428.449 us; speedup vs baseline: 4.4324x; 4.4324x over previous
//
#include <hip/hip_runtime.h>
#include <math.h>

#define N_NODES 20000
#define N_EDGES 400000
#define NH 10

// ---------------------------------------------------------------- helpers
__device__ __forceinline__ float gelu_f(float x) {
    float x3 = x * x * x;
    return 0.5f * x * (1.0f + tanhf(0.7978845608028654f * (x + 0.044715f * x3)));
}
__device__ __forceinline__ float elu_f(float x) {
    return x > 0.0f ? x : (expf(x) - 1.0f);
}

// ---------------------------------------------------------------- GEMM
// C[M,N] = act(A[M,K] @ W[K,N] + bias[N]); act: 0=none, 1=elu
template<int ACT>
__global__ __launch_bounds__(256) void gemm_kernel(
    const float* __restrict__ A, const float* __restrict__ W,
    const float* __restrict__ bias, float* __restrict__ C,
    int M, int N, int K)
{
    __shared__ float As[16][68];
    __shared__ float Bs[16][68];
    const int tid = threadIdx.x;
    const int m0 = blockIdx.y * 64;
    const int n0 = blockIdx.x * 64;
    const int tr = tid >> 4;           // 0..15
    const int tc = tid & 15;           // 0..15
    const int arow = tid >> 2;         // 0..63
    const int acol = (tid & 3) << 2;   // 0,4,8,12
    const int brow = tid >> 4;         // 0..15
    const int bcol = (tid & 15) << 2;  // 0..60
    const bool nvec = ((N & 3) == 0);

    float acc[4][4] = {};
    for (int k0 = 0; k0 < K; k0 += 16) {
        // A tile: 64 rows x 16 k (K is always a multiple of 16 here)
        {
            int m = m0 + arow;
            float4 v = make_float4(0.f, 0.f, 0.f, 0.f);
            if (m < M) v = *reinterpret_cast<const float4*>(A + (size_t)m * K + k0 + acol);
            As[acol + 0][arow] = v.x; As[acol + 1][arow] = v.y;
            As[acol + 2][arow] = v.z; As[acol + 3][arow] = v.w;
        }
        // B tile: 16 k x 64 n
        {
            int k = k0 + brow;
            const float* bp = W + (size_t)k * N + n0 + bcol;
            if (nvec && (n0 + bcol + 4 <= N)) {
                float4 v = *reinterpret_cast<const float4*>(bp);
                Bs[brow][bcol + 0] = v.x; Bs[brow][bcol + 1] = v.y;
                Bs[brow][bcol + 2] = v.z; Bs[brow][bcol + 3] = v.w;
            } else {
                #pragma unroll
                for (int j = 0; j < 4; ++j)
                    Bs[brow][bcol + j] = (n0 + bcol + j < N) ? bp[j] : 0.f;
            }
        }
        __syncthreads();
        #pragma unroll
        for (int kk = 0; kk < 16; ++kk) {
            float a[4], b[4];
            #pragma unroll
            for (int i = 0; i < 4; ++i) a[i] = As[kk][tr * 4 + i];
            #pragma unroll
            for (int j = 0; j < 4; ++j) b[j] = Bs[kk][tc * 4 + j];
            #pragma unroll
            for (int i = 0; i < 4; ++i)
                #pragma unroll
                for (int j = 0; j < 4; ++j)
                    acc[i][j] = fmaf(a[i], b[j], acc[i][j]);
        }
        __syncthreads();
    }
    #pragma unroll
    for (int i = 0; i < 4; ++i) {
        int m = m0 + tr * 4 + i;
        if (m >= M) continue;
        #pragma unroll
        for (int j = 0; j < 4; ++j) {
            int n = n0 + tc * 4 + j;
            if (n >= N) continue;
            float v = acc[i][j] + bias[n];
            if (ACT == 1) v = elu_f(v);
            C[(size_t)m * N + n] = v;
        }
    }
}

// ---------------------------------------------------------------- relation transform
// Y[n,h,e] = sum_d X[n,h,d] * R[h,d,e]   (R already offset to the relation)
__global__ void relt_kernel(const float* __restrict__ X, const float* __restrict__ R,
                            float* __restrict__ Y, int total, int D)
{
    int tid = blockIdx.x * blockDim.x + threadIdx.x;
    if (tid >= total) return;
    int dout = tid % D;
    int nh = tid / D;          // n*NH + h
    int h = nh % NH;
    const float* x = X + (size_t)nh * D;
    const float* r = R + (size_t)h * D * D + dout;
    float acc = 0.f;
    for (int d = 0; d < D; ++d) acc = fmaf(x[d], r[(size_t)d * D], acc);
    Y[tid] = acc;
}

// ---------------------------------------------------------------- fused edge pipeline
// One block per dst node (CSR order): logits for all its in-edges, segment
// softmax (chunked online), weighted aggregation of VR rows, gelu on output.
// Q[dst] staged in LDS; KR/VR rows read exactly once per edge.
template<int D>
__global__ __launch_bounds__(256) void edge_fused_kernel(
    const float* __restrict__ Q,    // [N, HD] dst-type q
    const float* __restrict__ KR,   // [N, HD] src-type k after relation transform
    const float* __restrict__ VR,   // [N, HD] src-type v after relation transform
    const int* __restrict__ rp, const int* __restrict__ srcA,
    const int* __restrict__ eidA, const float* __restrict__ ea,
    const float* __restrict__ prel, const float* __restrict__ ew,
    const float* __restrict__ eb,   // [NH] each, already relation-offset
    float* __restrict__ out,        // [N, HD], gelu applied
    float scale)
{
    constexpr int HD = NH * D;
    constexpr int C = 64;           // edge chunk; avg degree 20, max ~45
    __shared__ float q_s[HD];
    __shared__ float ls[C][NH];
    __shared__ int   srcs[C];
    __shared__ float eas[C];
    __shared__ float prel_s[NH], ew_s[NH], eb_s[NH];
    __shared__ float m_s[NH], s_s[NH], rexp_s[NH];

    const int dst = blockIdx.x;
    const int t = threadIdx.x;
    const int s0 = rp[dst], s1 = rp[dst + 1];
    const int deg = s1 - s0;

    // HD can exceed blockDim (HD=320 for D=32) -> stride loop, NOT `if (t<HD)`
    for (int i = t; i < HD; i += 256) q_s[i] = Q[(size_t)dst * HD + i];
    if (t < NH) { prel_s[t] = prel[t]; ew_s[t] = ew[t]; eb_s[t] = eb[t];
                  m_s[t] = -3.4e38f;  s_s[t] = 0.f; }
    float acc0 = 0.f, acc1 = 0.f;
    const int o0 = t, o1 = t + 256;
    __syncthreads();

    for (int base = 0; base < deg; base += C) {
        const int cl = min(C, deg - base);
        if (t < cl) {
            srcs[t] = srcA[s0 + base + t];
            eas[t]  = ea[eidA[s0 + base + t]];
        }
        __syncthreads();
        // logits for this chunk: thread item = p*NH + h
        for (int item = t; item < cl * NH; item += 256) {
            const int p = item / NH, h = item - p * NH;
            const float* kr = KR + (size_t)srcs[p] * HD + h * D;
            const float* q  = q_s + h * D;
            float d0 = 0.f;
            #pragma unroll
            for (int d = 0; d < D; ++d) d0 = fmaf(q[d], kr[d], d0);
            ls[p][h] = d0 * scale * prel_s[h] + eas[p] * ew_s[h] + eb_s[h];
        }
        __syncthreads();
        // per-head online softmax update (10 threads, <=64 serial iters)
        if (t < NH) {
            float cm = -3.4e38f;
            for (int p = 0; p < cl; ++p) cm = fmaxf(cm, ls[p][t]);
            float nm = fmaxf(m_s[t], cm);
            float r  = expf(m_s[t] - nm);
            float cs = 0.f;
            for (int p = 0; p < cl; ++p) {
                float w = expf(ls[p][t] - nm);
                ls[p][t] = w;
                cs += w;
            }
            s_s[t] = s_s[t] * r + cs;
            m_s[t] = nm;
            rexp_s[t] = r;
        }
        __syncthreads();
        // accumulate VR rows weighted by exp-logits (coalesced over o)
        if (o0 < HD) {
            const int h0 = o0 / D;
            acc0 *= rexp_s[h0];
            for (int p = 0; p < cl; ++p)
                acc0 = fmaf(ls[p][h0], VR[(size_t)srcs[p] * HD + o0], acc0);
        }
        if (o1 < HD) {
            const int h1 = o1 / D;
            acc1 *= rexp_s[h1];
            for (int p = 0; p < cl; ++p)
                acc1 = fmaf(ls[p][h1], VR[(size_t)srcs[p] * HD + o1], acc1);
        }
        __syncthreads();
    }
    if (o0 < HD) out[(size_t)dst * HD + o0] = gelu_f(acc0 / (s_s[o0 / D] + 1e-16f));
    if (o1 < HD) out[(size_t)dst * HD + o1] = gelu_f(acc1 / (s_s[o1 / D] + 1e-16f));
}

// ---------------------------------------------------------------- CSR build
__global__ void count_kernel(const int* __restrict__ ei, int* __restrict__ cnt)
{
    int e = blockIdx.x * blockDim.x + threadIdx.x;
    if (e < N_EDGES) atomicAdd(&cnt[ei[N_EDGES + e]], 1);
}

__global__ void scatter_kernel(const int* __restrict__ ei, int* __restrict__ cursor,
                               int* __restrict__ srcA, int* __restrict__ eidA)
{
    int e = blockIdx.x * blockDim.x + threadIdx.x;
    if (e >= N_EDGES) return;
    int dst = ei[N_EDGES + e];
    int pos = atomicAdd(&cursor[dst], 1);
    srcA[pos] = ei[e];
    eidA[pos] = e;
}

// single-block exclusive scan of n ints -> rp[0..n], also copies to cursor
__global__ void exscan_kernel(const int* __restrict__ cnt, int* __restrict__ rp,
                              int* __restrict__ cursor, int n)
{
    __shared__ int buf[1024];
    __shared__ int carry;
    int t = threadIdx.x;
    if (t == 0) carry = 0;
    __syncthreads();
    for (int base = 0; base < n; base += 1024) {
        int v = (base + t < n) ? cnt[base + t] : 0;
        buf[t] = v;
        __syncthreads();
        for (int off = 1; off < 1024; off <<= 1) {
            int x = (t >= off) ? buf[t - off] : 0;
            __syncthreads();
            buf[t] += x;
            __syncthreads();
        }
        int excl = buf[t] - v + carry;
        if (base + t < n) { rp[base + t] = excl; cursor[base + t] = excl; }
        int total = buf[1023];
        __syncthreads();
        if (t == 0) carry += total;
        __syncthreads();
    }
    if (t == 0) rp[n] = carry;
}

// ---------------------------------------------------------------- batchnorm
__global__ void colstat_kernel(const float* __restrict__ X, float* __restrict__ sums,
                               int M, int N)
{
    __shared__ float ls[256], lq[256];
    int c = blockIdx.x * 64 + (threadIdx.x & 63);
    int rl = threadIdx.x >> 6;
    float s = 0.f, q = 0.f;
    for (int r = blockIdx.y * 4 + rl; r < M; r += gridDim.y * 4) {
        float v = X[(size_t)r * N + c];
        s += v; q = fmaf(v, v, q);
    }
    ls[threadIdx.x] = s; lq[threadIdx.x] = q;
    __syncthreads();
    if (rl == 0) {
        s = ls[threadIdx.x] + ls[threadIdx.x + 64] + ls[threadIdx.x + 128] + ls[threadIdx.x + 192];
        q = lq[threadIdx.x] + lq[threadIdx.x + 64] + lq[threadIdx.x + 128] + lq[threadIdx.x + 192];
        atomicAdd(&sums[c], s);
        atomicAdd(&sums[N + c], q);
    }
}

__global__ void bn_kernel(float* __restrict__ X, const float* __restrict__ sums,
                          const float* __restrict__ g, const float* __restrict__ b,
                          int M, int N)
{
    int tid = blockIdx.x * blockDim.x + threadIdx.x;
    if (tid >= M * N) return;
    int c = tid % N;
    float mu = sums[c] / (float)M;
    float var = sums[N + c] / (float)M - mu * mu;
    X[tid] = (X[tid] - mu) * rsqrtf(var + 1e-5f) * g[c] + b[c];
}

// ---------------------------------------------------------------- output epilogues
__global__ void rownorm_kernel(const float* __restrict__ X, float* __restrict__ out)
{
    int row = blockIdx.x;
    int l = threadIdx.x;   // 64 threads
    const float* x = X + (size_t)row * 128;
    float v0 = x[l], v1 = x[l + 64];
    float ss = v0 * v0 + v1 * v1;
    #pragma unroll
    for (int off = 32; off; off >>= 1) ss += __shfl_xor(ss, off);
    float inv = rsqrtf(ss + 1e-12f);
    out[(size_t)row * 128 + l] = v0 * inv;
    out[(size_t)row * 128 + l + 64] = v1 * inv;
}

__global__ void rowsoftmax_kernel(const float* __restrict__ X, float* __restrict__ out)
{
    int row = blockIdx.x;
    int l = threadIdx.x;   // 64 threads, 129 columns
    const float* x = X + (size_t)row * 129;
    float v0 = x[l], v1 = x[l + 64];
    float v2 = (l == 0) ? x[128] : -3.4e38f;
    float m = fmaxf(fmaxf(v0, v1), v2);
    #pragma unroll
    for (int off = 32; off; off >>= 1) m = fmaxf(m, __shfl_xor(m, off));
    float e0 = expf(v0 - m), e1 = expf(v1 - m);
    float e2 = (l == 0) ? expf(v2 - m) : 0.f;
    float s = e0 + e1 + e2;
    #pragma unroll
    for (int off = 32; off; off >>= 1) s += __shfl_xor(s, off);
    float inv = 1.f / s;
    out[(size_t)row * 129 + l] = e0 * inv;
    out[(size_t)row * 129 + l + 64] = e1 * inv;
    if (l == 0) out[(size_t)row * 129 + 128] = e2 * inv;
}

// ---------------------------------------------------------------- host-side plumbing
static inline void launch_gemm(const float* A, const float* W, const float* bias, float* C,
                               int M, int N, int K, int act, hipStream_t s)
{
    dim3 grid((N + 63) / 64, (M + 63) / 64);
    if (act) gemm_kernel<1><<<grid, 256, 0, s>>>(A, W, bias, C, M, N, K);
    else     gemm_kernel<0><<<grid, 256, 0, s>>>(A, W, bias, C, M, N, K);
}

struct LayerParams {
    const float *kw, *kb, *qw, *qb, *vw, *vb, *arel, *mrel, *prel, *ew, *eb, *alw, *alb;
};

struct CsrRel { const int* rp; const int* src; const int* eid; };

template<int D>
static void run_layer(const LayerParams& P, int fin,
                      const float* xa, const float* xu,
                      float* B2, float* B3, float* B4, float* B5, float* B6, float* B7,
                      float* ya, float* yu,
                      const float* ea_au, const float* ea_ua,
                      const CsrRel& au, const CsrRel& ua, hipStream_t s)
{
    const int HD = NH * D;
    const float scale = 1.0f / sqrtf((float)D);
    const int nhd = N_NODES * HD;
    const int gNHD = (nhd + 255) / 256;

    // ---- relation ant->user (r=0): k/v from ant, q from user
    launch_gemm(xa, P.kw, P.kb, B2, N_NODES, HD, fin, 0, s);                         // k_a
    relt_kernel<<<gNHD, 256, 0, s>>>(B2, P.arel, B3, nhd, D);                        // kr_a
    launch_gemm(xa, P.vw, P.vb, B2, N_NODES, HD, fin, 0, s);                         // v_a
    relt_kernel<<<gNHD, 256, 0, s>>>(B2, P.mrel, B4, nhd, D);                        // vr_a
    launch_gemm(xu, P.qw + (size_t)fin * HD, P.qb + HD, B5, N_NODES, HD, fin, 0, s); // q_u
    edge_fused_kernel<D><<<N_NODES, 256, 0, s>>>(
        B5, B3, B4, au.rp, au.src, au.eid, ea_au,
        P.prel, P.ew, P.eb, B6, scale);                                              // B6 = gelu(agg_u)

    // ---- relation user->ant (r=1): k/v from user, q from ant
    launch_gemm(xu, P.kw + (size_t)fin * HD, P.kb + HD, B2, N_NODES, HD, fin, 0, s); // k_u
    relt_kernel<<<gNHD, 256, 0, s>>>(B2, P.arel + (size_t)NH * D * D, B3, nhd, D);   // kr_u
    launch_gemm(xu, P.vw + (size_t)fin * HD, P.vb + HD, B2, N_NODES, HD, fin, 0, s); // v_u
    relt_kernel<<<gNHD, 256, 0, s>>>(B2, P.mrel + (size_t)NH * D * D, B4, nhd, D);   // vr_u
    launch_gemm(xa, P.qw, P.qb, B5, N_NODES, HD, fin, 0, s);                         // q_a
    edge_fused_kernel<D><<<N_NODES, 256, 0, s>>>(
        B5, B3, B4, ua.rp, ua.src, ua.eid, ea_ua,
        P.prel + NH, P.ew + NH, P.eb + NH, B7, scale);                               // B7 = gelu(agg_a)

    // ---- per-type output linear (gelu already applied), elu-out
    launch_gemm(B7, P.alw, P.alb, ya, N_NODES, HD, HD, 1, s);                          // out_a
    launch_gemm(B6, P.alw + (size_t)HD * HD, P.alb + HD, yu, N_NODES, HD, HD, 1, s);   // out_u
}

extern "C" void kernel_launch(void* const* d_in, const int* in_sizes, int n_in,
                              void* d_out, int out_size, void* d_ws, size_t ws_size,
                              hipStream_t stream)
{
    // ---- inputs
    const float* x_ant  = (const float*)d_in[0];
    const float* x_user = (const float*)d_in[1];
    const float* ea_au  = (const float*)d_in[2];
    const float* ea_ua  = (const float*)d_in[3];
    LayerParams L1 = {
        (const float*)d_in[4],  (const float*)d_in[5],  (const float*)d_in[6],
        (const float*)d_in[7],  (const float*)d_in[8],  (const float*)d_in[9],
        (const float*)d_in[10], (const float*)d_in[11], (const float*)d_in[12],
        (const float*)d_in[13], (const float*)d_in[14], (const float*)d_in[15],
        (const float*)d_in[16]
    };
    LayerParams L2 = {
        (const float*)d_in[17], (const float*)d_in[18], (const float*)d_in[19],
        (const float*)d_in[20], (const float*)d_in[21], (const float*)d_in[22],
        (const float*)d_in[23], (const float*)d_in[24], (const float*)d_in[25],
        (const float*)d_in[26], (const float*)d_in[27], (const float*)d_in[28],
        (const float*)d_in[29]
    };
    const float* lin1_w  = (const float*)d_in[30];
    const float* lin1_b  = (const float*)d_in[31];
    const float* bn_g    = (const float*)d_in[32];
    const float* bn_b    = (const float*)d_in[33];
    const float* lin2_wa = (const float*)d_in[34];
    const float* lin2_ba = (const float*)d_in[35];
    const float* lin2_wu = (const float*)d_in[36];
    const float* lin2_bu = (const float*)d_in[37];
    const int*   ei_au   = (const int*)d_in[38];
    const int*   ei_ua   = (const int*)d_in[39];

    // ---- workspace arena (floats)
    float* F = (float*)d_ws;
    const size_t SLOT = (size_t)N_NODES * 320;
    float* B0 = F + 0 * SLOT;
    float* B1 = F + 1 * SLOT;
    float* B2 = F + 2 * SLOT;
    float* B3 = F + 3 * SLOT;
    float* B4 = F + 4 * SLOT;
    float* B5 = F + 5 * SLOT;
    float* B6 = F + 6 * SLOT;
    float* B7 = F + 7 * SLOT;
    float* STATS = F + 8 * SLOT;                       // 1024 (sum512 + sumsq512)
    int* I = (int*)(STATS + 1024);
    int* rp_au  = I;
    int* rp_ua  = rp_au + N_NODES + 1;
    int* src_au = rp_ua + N_NODES + 1;
    int* eid_au = src_au + N_EDGES;
    int* src_ua = eid_au + N_EDGES;
    int* eid_ua = src_ua + N_EDGES;
    int* cursor = eid_ua + N_EDGES;
    int* counts = cursor + N_NODES;

    const int gE = (N_EDGES + 255) / 256;

    // ---- CSR build (per relation, reused by both layers)
    hipMemsetAsync(counts, 0, N_NODES * sizeof(int), stream);
    count_kernel<<<gE, 256, 0, stream>>>(ei_au, counts);
    exscan_kernel<<<1, 1024, 0, stream>>>(counts, rp_au, cursor, N_NODES);
    scatter_kernel<<<gE, 256, 0, stream>>>(ei_au, cursor, src_au, eid_au);

    hipMemsetAsync(counts, 0, N_NODES * sizeof(int), stream);
    count_kernel<<<gE, 256, 0, stream>>>(ei_ua, counts);
    exscan_kernel<<<1, 1024, 0, stream>>>(counts, rp_ua, cursor, N_NODES);
    scatter_kernel<<<gE, 256, 0, stream>>>(ei_ua, cursor, src_ua, eid_ua);

    CsrRel au = { rp_au, src_au, eid_au };
    CsrRel ua = { rp_ua, src_ua, eid_ua };

    // ---- HGT layer 1: fin=128, D=16 -> outputs [N,160] in B0 (ant), B1 (user), elu applied
    run_layer<16>(L1, 128, x_ant, x_user, B2, B3, B4, B5, B6, B7, B0, B1,
                  ea_au, ea_ua, au, ua, stream);

    // ---- HGT layer 2: fin=160, D=32 -> outputs [N,320] in B0, B1, elu applied
    run_layer<32>(L2, 160, B0, B1, B2, B3, B4, B5, B6, B7, B0, B1,
                  ea_au, ea_ua, au, ua, stream);

    // ---- lin1 + elu:  [N,320] @ [320,512]
    float* L1A = B2;   // spans B2..B3 (N*512 floats)
    float* L1U = B4;   // spans B4..B5
    launch_gemm(B0, lin1_w, lin1_b, L1A, N_NODES, 512, 320, 1, stream);
    launch_gemm(B1, lin1_w + (size_t)320 * 512, lin1_b + 512, L1U, N_NODES, 512, 320, 1, stream);

    // ---- batchnorm (population stats over rows), in-place
    hipMemsetAsync(STATS, 0, 1024 * sizeof(float), stream);
    colstat_kernel<<<dim3(8, 32), 256, 0, stream>>>(L1A, STATS, N_NODES, 512);
    bn_kernel<<<(N_NODES * 512 + 255) / 256, 256, 0, stream>>>(L1A, STATS, bn_g, bn_b,
                                                               N_NODES, 512);
    hipMemsetAsync(STATS, 0, 1024 * sizeof(float), stream);
    colstat_kernel<<<dim3(8, 32), 256, 0, stream>>>(L1U, STATS, N_NODES, 512);
    bn_kernel<<<(N_NODES * 512 + 255) / 256, 256, 0, stream>>>(L1U, STATS, bn_g + 512,
                                                               bn_b + 512, N_NODES, 512);

    // ---- lin2 + output epilogues
    float* OUTA = B6;  // [N,128]
    float* OUTU = B7;  // [N,129]
    launch_gemm(L1A, lin2_wa, lin2_ba, OUTA, N_NODES, 128, 512, 0, stream);
    rownorm_kernel<<<N_NODES, 64, 0, stream>>>(OUTA, (float*)d_out);
    launch_gemm(L1U, lin2_wu, lin2_bu, OUTU, N_NODES, 129, 512, 0, stream);
    rowsoftmax_kernel<<<N_NODES, 64, 0, stream>>>(
        OUTU, (float*)d_out + (size_t)N_NODES * 128);
}

// Round 4
// 2046.353 us; speedup vs baseline: 5.2601x; 1.1867x over previous
//
#include <hip/hip_runtime.h>
#include <math.h>

#define N_NODES 20000
#define N_EDGES 400000
#define NH 10

// ---------------------------------------------------------------- helpers
__device__ __forceinline__ float gelu_f(float x) {
    float x3 = x * x * x;
    return 0.5f * x * (1.0f + tanhf(0.7978845608028654f * (x + 0.044715f * x3)));
}
__device__ __forceinline__ float elu_f(float x) {
    return x > 0.0f ? x : (expf(x) - 1.0f);
}

// ---------------------------------------------------------------- GEMM
// C[M,N] = act(A[M,K] @ W[K,N] + bias[N]); act: 0=none, 1=elu
// BM=128, BN=64, BK=32; 256 threads; 8x4 per-thread tile.
// K must be a multiple of 32 (all our K: 128,160,320,512).
template<int ACT>
__global__ __launch_bounds__(256) void gemm_kernel(
    const float* __restrict__ A, const float* __restrict__ W,
    const float* __restrict__ bias, float* __restrict__ C,
    int M, int N, int K)
{
    __shared__ float As[32][132];   // pitch 132 floats = 528B (16B-aligned rows)
    __shared__ float Bs[32][68];    // pitch 68 floats = 272B (16B-aligned rows)
    const int tid = threadIdx.x;
    const int m0 = blockIdx.y * 128;
    const int n0 = blockIdx.x * 64;
    const int tr = tid >> 4;            // 0..15 -> rows tr*8..tr*8+7
    const int tc = tid & 15;            // 0..15 -> cols tc*4..tc*4+3
    const int am = tid >> 1;            // 0..127 A row within tile
    const int ak = (tid & 1) * 16;      // k base 0 or 16
    const int bk = tid >> 4;            // 0..15 B k row (and +16)
    const int bn = (tid & 15) * 4;      // 0..60 B col
    const bool nvec = ((N & 3) == 0);
    const int mrow = m0 + am;

    float acc[8][4] = {};
    for (int k0 = 0; k0 < K; k0 += 32) {
        // A tile: 128 rows x 32 k, stored transposed As[k][m]
        #pragma unroll
        for (int j = 0; j < 4; ++j) {
            float4 v = make_float4(0.f, 0.f, 0.f, 0.f);
            if (mrow < M)
                v = *reinterpret_cast<const float4*>(A + (size_t)mrow * K + k0 + ak + j * 4);
            As[ak + j * 4 + 0][am] = v.x; As[ak + j * 4 + 1][am] = v.y;
            As[ak + j * 4 + 2][am] = v.z; As[ak + j * 4 + 3][am] = v.w;
        }
        // B tile: 32 k x 64 n
        #pragma unroll
        for (int j = 0; j < 2; ++j) {
            const int kk2 = bk + j * 16;
            const float* bp = W + (size_t)(k0 + kk2) * N + n0 + bn;
            if (nvec && (n0 + bn + 4 <= N)) {
                *reinterpret_cast<float4*>(&Bs[kk2][bn]) =
                    *reinterpret_cast<const float4*>(bp);
            } else {
                #pragma unroll
                for (int q = 0; q < 4; ++q)
                    Bs[kk2][bn + q] = (n0 + bn + q < N) ? bp[q] : 0.f;
            }
        }
        __syncthreads();
        #pragma unroll
        for (int kk = 0; kk < 32; ++kk) {
            float a[8], b[4];
            #pragma unroll
            for (int i = 0; i < 8; ++i) a[i] = As[kk][tr * 8 + i];
            #pragma unroll
            for (int j = 0; j < 4; ++j) b[j] = Bs[kk][tc * 4 + j];
            #pragma unroll
            for (int i = 0; i < 8; ++i)
                #pragma unroll
                for (int j = 0; j < 4; ++j)
                    acc[i][j] = fmaf(a[i], b[j], acc[i][j]);
        }
        __syncthreads();
    }
    #pragma unroll
    for (int i = 0; i < 8; ++i) {
        const int m = m0 + tr * 8 + i;
        if (m >= M) continue;
        #pragma unroll
        for (int j = 0; j < 4; ++j) {
            const int n = n0 + tc * 4 + j;
            if (n >= N) continue;
            float v = acc[i][j] + bias[n];
            if (ACT == 1) v = elu_f(v);
            C[(size_t)m * N + n] = v;
        }
    }
}

// ---------------------------------------------------------------- fused K/V weight precompute
// Wf[f][h*D+e] = sum_d KW[f][h*D+d] * REL[h][d][e], row f==fin holds the fused bias
// (from kb). Folds the per-node relation transform into the projection weight.
__global__ void fuse_w_kernel(const float* __restrict__ KW, const float* __restrict__ kb,
                              const float* __restrict__ REL, float* __restrict__ Wf,
                              int fin, int D, int HD)
{
    const int total = (fin + 1) * HD;
    int tid = blockIdx.x * blockDim.x + threadIdx.x;
    if (tid >= total) return;
    const int col = tid % HD, f = tid / HD;
    const int h = col / D, e = col - h * D;
    const float* src = (f < fin) ? KW + (size_t)f * HD + h * D : kb + h * D;
    const float* r = REL + (size_t)h * D * D + e;   // stride D over d
    float acc = 0.f;
    for (int d = 0; d < D; ++d) acc = fmaf(src[d], r[(size_t)d * D], acc);
    Wf[tid] = acc;
}

// ---------------------------------------------------------------- fused edge pipeline
// One block per dst node (CSR order): logits for all its in-edges, segment
// softmax (chunked online, 16 lanes per head), weighted aggregation of VR rows,
// gelu on output. Q[dst] staged in LDS; KR/VR rows read once per edge.
template<int D>
__global__ __launch_bounds__(256) void edge_fused_kernel(
    const float* __restrict__ Q,    // [N, HD] dst-type q
    const float* __restrict__ KR,   // [N, HD] src-type k after relation transform
    const float* __restrict__ VR,   // [N, HD] src-type v after relation transform
    const int* __restrict__ rp, const int* __restrict__ srcA,
    const int* __restrict__ eidA, const float* __restrict__ ea,
    const float* __restrict__ prel, const float* __restrict__ ew,
    const float* __restrict__ eb,   // [NH] each, already relation-offset
    float* __restrict__ out,        // [N, HD], gelu applied
    float scale)
{
    constexpr int HD = NH * D;
    constexpr int C = 64;           // edge chunk; avg degree 20, max ~50
    __shared__ float q_s[HD];
    __shared__ float ls[C][NH];
    __shared__ int   srcs[C];
    __shared__ float eas[C];
    __shared__ float prel_s[NH], ew_s[NH], eb_s[NH];
    __shared__ float m_s[NH], s_s[NH], rexp_s[NH];

    const int dst = blockIdx.x;
    const int t = threadIdx.x;
    const int s0 = rp[dst], s1 = rp[dst + 1];
    const int deg = s1 - s0;

    // HD can exceed blockDim (HD=320 for D=32) -> stride loop
    for (int i = t; i < HD; i += 256) q_s[i] = Q[(size_t)dst * HD + i];
    if (t < NH) { prel_s[t] = prel[t]; ew_s[t] = ew[t]; eb_s[t] = eb[t];
                  m_s[t] = -3.4e38f;  s_s[t] = 0.f; }
    float acc0 = 0.f, acc1 = 0.f;
    const int o0 = t, o1 = t + 256;
    __syncthreads();

    for (int base = 0; base < deg; base += C) {
        const int cl = min(C, deg - base);
        if (t < cl) {
            srcs[t] = srcA[s0 + base + t];
            eas[t]  = ea[eidA[s0 + base + t]];
        }
        __syncthreads();
        // logits for this chunk: thread item = p*NH + h
        for (int item = t; item < cl * NH; item += 256) {
            const int p = item / NH, h = item - p * NH;
            const float* kr = KR + (size_t)srcs[p] * HD + h * D;
            const float* q  = q_s + h * D;
            float d0 = 0.f;
            #pragma unroll
            for (int d = 0; d < D; ++d) d0 = fmaf(q[d], kr[d], d0);
            ls[p][h] = d0 * scale * prel_s[h] + eas[p] * ew_s[h] + eb_s[h];
        }
        __syncthreads();
        // per-head online softmax: 16 lanes per head (lane-aligned groups)
        if (t < NH * 16) {
            const int h = t >> 4, sub = t & 15;
            float cm = -3.4e38f;
            for (int p = sub; p < cl; p += 16) cm = fmaxf(cm, ls[p][h]);
            #pragma unroll
            for (int off = 8; off; off >>= 1) cm = fmaxf(cm, __shfl_xor(cm, off));
            const float nm = fmaxf(m_s[h], cm);
            float cs = 0.f;
            for (int p = sub; p < cl; p += 16) {
                float w = expf(ls[p][h] - nm);
                ls[p][h] = w;
                cs += w;
            }
            #pragma unroll
            for (int off = 8; off; off >>= 1) cs += __shfl_xor(cs, off);
            if (sub == 0) {
                const float r = expf(m_s[h] - nm);
                s_s[h] = s_s[h] * r + cs;
                m_s[h] = nm;
                rexp_s[h] = r;
            }
        }
        __syncthreads();
        // accumulate VR rows weighted by exp-logits (coalesced over o)
        if (o0 < HD) {
            const int h0 = o0 / D;
            acc0 *= rexp_s[h0];
            for (int p = 0; p < cl; ++p)
                acc0 = fmaf(ls[p][h0], VR[(size_t)srcs[p] * HD + o0], acc0);
        }
        if (o1 < HD) {
            const int h1 = o1 / D;
            acc1 *= rexp_s[h1];
            for (int p = 0; p < cl; ++p)
                acc1 = fmaf(ls[p][h1], VR[(size_t)srcs[p] * HD + o1], acc1);
        }
        __syncthreads();
    }
    if (o0 < HD) out[(size_t)dst * HD + o0] = gelu_f(acc0 / (s_s[o0 / D] + 1e-16f));
    if (o1 < HD) out[(size_t)dst * HD + o1] = gelu_f(acc1 / (s_s[o1 / D] + 1e-16f));
}

// ---------------------------------------------------------------- CSR build
__global__ void count_kernel(const int* __restrict__ ei, int* __restrict__ cnt)
{
    int e = blockIdx.x * blockDim.x + threadIdx.x;
    if (e < N_EDGES) atomicAdd(&cnt[ei[N_EDGES + e]], 1);
}

__global__ void scatter_kernel(const int* __restrict__ ei, int* __restrict__ cursor,
                               int* __restrict__ srcA, int* __restrict__ eidA)
{
    int e = blockIdx.x * blockDim.x + threadIdx.x;
    if (e >= N_EDGES) return;
    int dst = ei[N_EDGES + e];
    int pos = atomicAdd(&cursor[dst], 1);
    srcA[pos] = ei[e];
    eidA[pos] = e;
}

// single-block exclusive scan of n ints -> rp[0..n], also copies to cursor
__global__ void exscan_kernel(const int* __restrict__ cnt, int* __restrict__ rp,
                              int* __restrict__ cursor, int n)
{
    __shared__ int buf[1024];
    __shared__ int carry;
    int t = threadIdx.x;
    if (t == 0) carry = 0;
    __syncthreads();
    for (int base = 0; base < n; base += 1024) {
        int v = (base + t < n) ? cnt[base + t] : 0;
        buf[t] = v;
        __syncthreads();
        for (int off = 1; off < 1024; off <<= 1) {
            int x = (t >= off) ? buf[t - off] : 0;
            __syncthreads();
            buf[t] += x;
            __syncthreads();
        }
        int excl = buf[t] - v + carry;
        if (base + t < n) { rp[base + t] = excl; cursor[base + t] = excl; }
        int total = buf[1023];
        __syncthreads();
        if (t == 0) carry += total;
        __syncthreads();
    }
    if (t == 0) rp[n] = carry;
}

// ---------------------------------------------------------------- batchnorm
__global__ void colstat_kernel(const float* __restrict__ X, float* __restrict__ sums,
                               int M, int N)
{
    __shared__ float ls[256], lq[256];
    int c = blockIdx.x * 64 + (threadIdx.x & 63);
    int rl = threadIdx.x >> 6;
    float s = 0.f, q = 0.f;
    for (int r = blockIdx.y * 4 + rl; r < M; r += gridDim.y * 4) {
        float v = X[(size_t)r * N + c];
        s += v; q = fmaf(v, v, q);
    }
    ls[threadIdx.x] = s; lq[threadIdx.x] = q;
    __syncthreads();
    if (rl == 0) {
        s = ls[threadIdx.x] + ls[threadIdx.x + 64] + ls[threadIdx.x + 128] + ls[threadIdx.x + 192];
        q = lq[threadIdx.x] + lq[threadIdx.x + 64] + lq[threadIdx.x + 128] + lq[threadIdx.x + 192];
        atomicAdd(&sums[c], s);
        atomicAdd(&sums[N + c], q);
    }
}

__global__ void bn_kernel(float* __restrict__ X, const float* __restrict__ sums,
                          const float* __restrict__ g, const float* __restrict__ b,
                          int M, int N)
{
    int tid = blockIdx.x * blockDim.x + threadIdx.x;
    if (tid >= M * N) return;
    int c = tid % N;
    float mu = sums[c] / (float)M;
    float var = sums[N + c] / (float)M - mu * mu;
    X[tid] = (X[tid] - mu) * rsqrtf(var + 1e-5f) * g[c] + b[c];
}

// ---------------------------------------------------------------- output epilogues
__global__ void rownorm_kernel(const float* __restrict__ X, float* __restrict__ out)
{
    int row = blockIdx.x;
    int l = threadIdx.x;   // 64 threads
    const float* x = X + (size_t)row * 128;
    float v0 = x[l], v1 = x[l + 64];
    float ss = v0 * v0 + v1 * v1;
    #pragma unroll
    for (int off = 32; off; off >>= 1) ss += __shfl_xor(ss, off);
    float inv = rsqrtf(ss + 1e-12f);
    out[(size_t)row * 128 + l] = v0 * inv;
    out[(size_t)row * 128 + l + 64] = v1 * inv;
}

__global__ void rowsoftmax_kernel(const float* __restrict__ X, float* __restrict__ out)
{
    int row = blockIdx.x;
    int l = threadIdx.x;   // 64 threads, 129 columns
    const float* x = X + (size_t)row * 129;
    float v0 = x[l], v1 = x[l + 64];
    float v2 = (l == 0) ? x[128] : -3.4e38f;
    float m = fmaxf(fmaxf(v0, v1), v2);
    #pragma unroll
    for (int off = 32; off; off >>= 1) m = fmaxf(m, __shfl_xor(m, off));
    float e0 = expf(v0 - m), e1 = expf(v1 - m);
    float e2 = (l == 0) ? expf(v2 - m) : 0.f;
    float s = e0 + e1 + e2;
    #pragma unroll
    for (int off = 32; off; off >>= 1) s += __shfl_xor(s, off);
    float inv = 1.f / s;
    out[(size_t)row * 129 + l] = e0 * inv;
    out[(size_t)row * 129 + l + 64] = e1 * inv;
    if (l == 0) out[(size_t)row * 129 + 128] = e2 * inv;
}

// ---------------------------------------------------------------- host-side plumbing
static inline void launch_gemm(const float* A, const float* W, const float* bias, float* C,
                               int M, int N, int K, int act, hipStream_t s)
{
    dim3 grid((N + 63) / 64, (M + 127) / 128);
    if (act) gemm_kernel<1><<<grid, 256, 0, s>>>(A, W, bias, C, M, N, K);
    else     gemm_kernel<0><<<grid, 256, 0, s>>>(A, W, bias, C, M, N, K);
}

struct LayerParams {
    const float *kw, *kb, *qw, *qb, *vw, *vb, *arel, *mrel, *prel, *ew, *eb, *alw, *alb;
};

struct CsrRel { const int* rp; const int* src; const int* eid; };

template<int D>
static void run_layer(const LayerParams& P, int fin,
                      const float* xa, const float* xu,
                      float* B3, float* B4, float* B5, float* B6, float* B7,
                      float* WFK, float* WFV,
                      float* ya, float* yu,
                      const float* ea_au, const float* ea_ua,
                      const CsrRel& au, const CsrRel& ua, hipStream_t s)
{
    const int HD = NH * D;
    const float scale = 1.0f / sqrtf((float)D);
    const int gFW = ((fin + 1) * HD + 255) / 256;

    // ---- relation ant->user (r=0): k/v from ant (type 0, arel/mrel[0]), q from user
    fuse_w_kernel<<<gFW, 256, 0, s>>>(P.kw, P.kb, P.arel, WFK, fin, D, HD);
    fuse_w_kernel<<<gFW, 256, 0, s>>>(P.vw, P.vb, P.mrel, WFV, fin, D, HD);
    launch_gemm(xa, WFK, WFK + (size_t)fin * HD, B3, N_NODES, HD, fin, 0, s);         // kr_a
    launch_gemm(xa, WFV, WFV + (size_t)fin * HD, B4, N_NODES, HD, fin, 0, s);         // vr_a
    launch_gemm(xu, P.qw + (size_t)fin * HD, P.qb + HD, B5, N_NODES, HD, fin, 0, s);  // q_u
    edge_fused_kernel<D><<<N_NODES, 256, 0, s>>>(
        B5, B3, B4, au.rp, au.src, au.eid, ea_au,
        P.prel, P.ew, P.eb, B6, scale);                                               // B6 = gelu(agg_u)

    // ---- relation user->ant (r=1): k/v from user (type 1, arel/mrel[1]), q from ant
    fuse_w_kernel<<<gFW, 256, 0, s>>>(P.kw + (size_t)fin * HD, P.kb + HD,
                                      P.arel + (size_t)NH * D * D, WFK, fin, D, HD);
    fuse_w_kernel<<<gFW, 256, 0, s>>>(P.vw + (size_t)fin * HD, P.vb + HD,
                                      P.mrel + (size_t)NH * D * D, WFV, fin, D, HD);
    launch_gemm(xu, WFK, WFK + (size_t)fin * HD, B3, N_NODES, HD, fin, 0, s);         // kr_u
    launch_gemm(xu, WFV, WFV + (size_t)fin * HD, B4, N_NODES, HD, fin, 0, s);         // vr_u
    launch_gemm(xa, P.qw, P.qb, B5, N_NODES, HD, fin, 0, s);                          // q_a
    edge_fused_kernel<D><<<N_NODES, 256, 0, s>>>(
        B5, B3, B4, ua.rp, ua.src, ua.eid, ea_ua,
        P.prel + NH, P.ew + NH, P.eb + NH, B7, scale);                                // B7 = gelu(agg_a)

    // ---- per-type output linear (gelu already applied inside edge kernel), elu-out
    launch_gemm(B7, P.alw, P.alb, ya, N_NODES, HD, HD, 1, s);                          // out_a
    launch_gemm(B6, P.alw + (size_t)HD * HD, P.alb + HD, yu, N_NODES, HD, HD, 1, s);   // out_u
}

extern "C" void kernel_launch(void* const* d_in, const int* in_sizes, int n_in,
                              void* d_out, int out_size, void* d_ws, size_t ws_size,
                              hipStream_t stream)
{
    // ---- inputs
    const float* x_ant  = (const float*)d_in[0];
    const float* x_user = (const float*)d_in[1];
    const float* ea_au  = (const float*)d_in[2];
    const float* ea_ua  = (const float*)d_in[3];
    LayerParams L1 = {
        (const float*)d_in[4],  (const float*)d_in[5],  (const float*)d_in[6],
        (const float*)d_in[7],  (const float*)d_in[8],  (const float*)d_in[9],
        (const float*)d_in[10], (const float*)d_in[11], (const float*)d_in[12],
        (const float*)d_in[13], (const float*)d_in[14], (const float*)d_in[15],
        (const float*)d_in[16]
    };
    LayerParams L2 = {
        (const float*)d_in[17], (const float*)d_in[18], (const float*)d_in[19],
        (const float*)d_in[20], (const float*)d_in[21], (const float*)d_in[22],
        (const float*)d_in[23], (const float*)d_in[24], (const float*)d_in[25],
        (const float*)d_in[26], (const float*)d_in[27], (const float*)d_in[28],
        (const float*)d_in[29]
    };
    const float* lin1_w  = (const float*)d_in[30];
    const float* lin1_b  = (const float*)d_in[31];
    const float* bn_g    = (const float*)d_in[32];
    const float* bn_b    = (const float*)d_in[33];
    const float* lin2_wa = (const float*)d_in[34];
    const float* lin2_ba = (const float*)d_in[35];
    const float* lin2_wu = (const float*)d_in[36];
    const float* lin2_bu = (const float*)d_in[37];
    const int*   ei_au   = (const int*)d_in[38];
    const int*   ei_ua   = (const int*)d_in[39];

    // ---- workspace arena (floats)
    float* F = (float*)d_ws;
    const size_t SLOT = (size_t)N_NODES * 320;
    float* B0 = F + 0 * SLOT;
    float* B1 = F + 1 * SLOT;
    float* B2 = F + 2 * SLOT;
    float* B3 = F + 3 * SLOT;
    float* B4 = F + 4 * SLOT;
    float* B5 = F + 5 * SLOT;
    float* B6 = F + 6 * SLOT;
    float* B7 = F + 7 * SLOT;
    float* STATS = F + 8 * SLOT;                       // 1024 (sum512 + sumsq512)
    int* I = (int*)(STATS + 1024);
    int* rp_au  = I;
    int* rp_ua  = rp_au + N_NODES + 1;
    int* src_au = rp_ua + N_NODES + 1;
    int* eid_au = src_au + N_EDGES;
    int* src_ua = eid_au + N_EDGES;
    int* eid_ua = src_ua + N_EDGES;
    int* cursor = eid_ua + N_EDGES;
    int* counts = cursor + N_NODES;
    float* WFK = (float*)(counts + N_NODES);           // (fin+1)*HD <= 161*320
    float* WFV = WFK + 161 * 320;

    const int gE = (N_EDGES + 255) / 256;

    // ---- CSR build (per relation, reused by both layers)
    hipMemsetAsync(counts, 0, N_NODES * sizeof(int), stream);
    count_kernel<<<gE, 256, 0, stream>>>(ei_au, counts);
    exscan_kernel<<<1, 1024, 0, stream>>>(counts, rp_au, cursor, N_NODES);
    scatter_kernel<<<gE, 256, 0, stream>>>(ei_au, cursor, src_au, eid_au);

    hipMemsetAsync(counts, 0, N_NODES * sizeof(int), stream);
    count_kernel<<<gE, 256, 0, stream>>>(ei_ua, counts);
    exscan_kernel<<<1, 1024, 0, stream>>>(counts, rp_ua, cursor, N_NODES);
    scatter_kernel<<<gE, 256, 0, stream>>>(ei_ua, cursor, src_ua, eid_ua);

    CsrRel au = { rp_au, src_au, eid_au };
    CsrRel ua = { rp_ua, src_ua, eid_ua };

    // ---- HGT layer 1: fin=128, D=16 -> outputs [N,160] in B0 (ant), B1 (user), elu applied
    run_layer<16>(L1, 128, x_ant, x_user, B3, B4, B5, B6, B7, WFK, WFV, B0, B1,
                  ea_au, ea_ua, au, ua, stream);

    // ---- HGT layer 2: fin=160, D=32 -> outputs [N,320] in B0, B1, elu applied
    run_layer<32>(L2, 160, B0, B1, B3, B4, B5, B6, B7, WFK, WFV, B0, B1,
                  ea_au, ea_ua, au, ua, stream);

    // ---- lin1 + elu:  [N,320] @ [320,512]
    float* L1A = B2;   // spans B2..B3 (N*512 floats)
    float* L1U = B4;   // spans B4..B5
    launch_gemm(B0, lin1_w, lin1_b, L1A, N_NODES, 512, 320, 1, stream);
    launch_gemm(B1, lin1_w + (size_t)320 * 512, lin1_b + 512, L1U, N_NODES, 512, 320, 1, stream);

    // ---- batchnorm (population stats over rows), in-place
    hipMemsetAsync(STATS, 0, 1024 * sizeof(float), stream);
    colstat_kernel<<<dim3(8, 32), 256, 0, stream>>>(L1A, STATS, N_NODES, 512);
    bn_kernel<<<(N_NODES * 512 + 255) / 256, 256, 0, stream>>>(L1A, STATS, bn_g, bn_b,
                                                               N_NODES, 512);
    hipMemsetAsync(STATS, 0, 1024 * sizeof(float), stream);
    colstat_kernel<<<dim3(8, 32), 256, 0, stream>>>(L1U, STATS, N_NODES, 512);
    bn_kernel<<<(N_NODES * 512 + 255) / 256, 256, 0, stream>>>(L1U, STATS, bn_g + 512,
                                                               bn_b + 512, N_NODES, 512);

    // ---- lin2 + output epilogues
    float* OUTA = B6;  // [N,128]
    float* OUTU = B7;  // [N,129]
    launch_gemm(L1A, lin2_wa, lin2_ba, OUTA, N_NODES, 128, 512, 0, stream);
    rownorm_kernel<<<N_NODES, 64, 0, stream>>>(OUTA, (float*)d_out);
    launch_gemm(L1U, lin2_wu, lin2_bu, OUTU, N_NODES, 129, 512, 0, stream);
    rowsoftmax_kernel<<<N_NODES, 64, 0, stream>>>(
        OUTU, (float*)d_out + (size_t)N_NODES * 128);
}

// Round 5
// 1862.456 us; speedup vs baseline: 5.7794x; 1.0987x over previous
//
#include <hip/hip_runtime.h>
#include <hip/hip_bf16.h>
#include <math.h>

#define N_NODES 20000
#define N_EDGES 400000
#define NH 10

// ---------------------------------------------------------------- helpers
__device__ __forceinline__ float gelu_f(float x) {
    float x3 = x * x * x;
    return 0.5f * x * (1.0f + tanhf(0.7978845608028654f * (x + 0.044715f * x3)));
}
__device__ __forceinline__ float elu_f(float x) {
    return x > 0.0f ? x : (expf(x) - 1.0f);
}
__device__ __forceinline__ float bf_lo(unsigned int w) {
    return __uint_as_float(w << 16);
}
__device__ __forceinline__ float bf_hi(unsigned int w) {
    return __uint_as_float(w & 0xffff0000u);
}

// ---------------------------------------------------------------- GEMM
// C[M,N] = act(A[M,K] @ W[K,N] + bias[N]); act: 0=none, 1=elu
// OUT: float or __hip_bfloat16 output. BM=128, BN=64, BK=32; 256 thr; 8x4/thread.
// K must be a multiple of 32 (all our K: 128,160,320,512).
template<int ACT, typename OUT>
__global__ __launch_bounds__(256) void gemm_kernel(
    const float* __restrict__ A, const float* __restrict__ W,
    const float* __restrict__ bias, OUT* __restrict__ C,
    int M, int N, int K)
{
    __shared__ float As[32][132];   // pitch 132 floats (16B-aligned rows)
    __shared__ float Bs[32][68];
    const int tid = threadIdx.x;
    const int m0 = blockIdx.y * 128;
    const int n0 = blockIdx.x * 64;
    const int tr = tid >> 4;            // 0..15 -> rows tr*8..tr*8+7
    const int tc = tid & 15;            // 0..15 -> cols tc*4..tc*4+3
    const int am = tid >> 1;            // 0..127 A row within tile
    const int ak = (tid & 1) * 16;      // k base 0 or 16
    const int bk = tid >> 4;            // 0..15 B k row (and +16)
    const int bn = (tid & 15) * 4;      // 0..60 B col
    const bool nvec = ((N & 3) == 0);
    const int mrow = m0 + am;

    float acc[8][4] = {};
    for (int k0 = 0; k0 < K; k0 += 32) {
        #pragma unroll
        for (int j = 0; j < 4; ++j) {
            float4 v = make_float4(0.f, 0.f, 0.f, 0.f);
            if (mrow < M)
                v = *reinterpret_cast<const float4*>(A + (size_t)mrow * K + k0 + ak + j * 4);
            As[ak + j * 4 + 0][am] = v.x; As[ak + j * 4 + 1][am] = v.y;
            As[ak + j * 4 + 2][am] = v.z; As[ak + j * 4 + 3][am] = v.w;
        }
        #pragma unroll
        for (int j = 0; j < 2; ++j) {
            const int kk2 = bk + j * 16;
            const float* bp = W + (size_t)(k0 + kk2) * N + n0 + bn;
            if (nvec && (n0 + bn + 4 <= N)) {
                *reinterpret_cast<float4*>(&Bs[kk2][bn]) =
                    *reinterpret_cast<const float4*>(bp);
            } else {
                #pragma unroll
                for (int q = 0; q < 4; ++q)
                    Bs[kk2][bn + q] = (n0 + bn + q < N) ? bp[q] : 0.f;
            }
        }
        __syncthreads();
        #pragma unroll
        for (int kk = 0; kk < 32; ++kk) {
            float a[8], b[4];
            #pragma unroll
            for (int i = 0; i < 8; ++i) a[i] = As[kk][tr * 8 + i];
            #pragma unroll
            for (int j = 0; j < 4; ++j) b[j] = Bs[kk][tc * 4 + j];
            #pragma unroll
            for (int i = 0; i < 8; ++i)
                #pragma unroll
                for (int j = 0; j < 4; ++j)
                    acc[i][j] = fmaf(a[i], b[j], acc[i][j]);
        }
        __syncthreads();
    }
    #pragma unroll
    for (int i = 0; i < 8; ++i) {
        const int m = m0 + tr * 8 + i;
        if (m >= M) continue;
        #pragma unroll
        for (int j = 0; j < 4; ++j) {
            const int n = n0 + tc * 4 + j;
            if (n >= N) continue;
            float v = acc[i][j] + bias[n];
            if (ACT == 1) v = elu_f(v);
            if constexpr (sizeof(OUT) == 2)
                C[(size_t)m * N + n] = __float2bfloat16(v);
            else
                C[(size_t)m * N + n] = v;
        }
    }
}

// ---------------------------------------------------------------- fused K/V weight precompute
// Wf[f][h*D+e] = sum_d KW[f][h*D+d] * REL[h][d][e]; row f==fin holds fused bias.
__global__ void fuse_w_kernel(const float* __restrict__ KW, const float* __restrict__ kb,
                              const float* __restrict__ REL, float* __restrict__ Wf,
                              int fin, int D, int HD)
{
    const int total = (fin + 1) * HD;
    int tid = blockIdx.x * blockDim.x + threadIdx.x;
    if (tid >= total) return;
    const int col = tid % HD, f = tid / HD;
    const int h = col / D, e = col - h * D;
    const float* src = (f < fin) ? KW + (size_t)f * HD + h * D : kb + h * D;
    const float* r = REL + (size_t)h * D * D + e;   // stride D over d
    float acc = 0.f;
    for (int d = 0; d < D; ++d) acc = fmaf(src[d], r[(size_t)d * D], acc);
    Wf[tid] = acc;
}

// ---------------------------------------------------------------- fused edge pipeline
// One block per dst node (CSR order): logits, chunked online segment softmax
// (16 lanes/head), weighted aggregation, gelu. Q[dst] fp32 in LDS; KR/VR are
// bf16 tables, read once per edge; accumulation fp32.
template<int D>
__global__ __launch_bounds__(256) void edge_fused_kernel(
    const float* __restrict__ Q,                // [N, HD] fp32
    const __hip_bfloat16* __restrict__ KR,      // [N, HD] bf16
    const __hip_bfloat16* __restrict__ VR,      // [N, HD] bf16
    const int* __restrict__ rp, const int* __restrict__ srcA,
    const int* __restrict__ eidA, const float* __restrict__ ea,
    const float* __restrict__ prel, const float* __restrict__ ew,
    const float* __restrict__ eb,               // [NH], relation-offset
    float* __restrict__ out,                    // [N, HD], gelu applied
    float scale)
{
    constexpr int HD = NH * D;
    constexpr int PAIRS = HD / 2;   // 80 (D=16) or 160 (D=32)
    constexpr int C = 64;           // edge chunk; avg degree 20, max ~50
    __shared__ float q_s[HD];
    __shared__ float ls[C][NH];
    __shared__ int   srcs[C];
    __shared__ float eas[C];
    __shared__ float prel_s[NH], ew_s[NH], eb_s[NH];
    __shared__ float m_s[NH], s_s[NH], rexp_s[NH];

    const int dst = blockIdx.x;
    const int t = threadIdx.x;
    const int s0 = rp[dst], s1 = rp[dst + 1];
    const int deg = s1 - s0;

    for (int i = t; i < HD; i += 256) q_s[i] = Q[(size_t)dst * HD + i];
    if (t < NH) { prel_s[t] = prel[t]; ew_s[t] = ew[t]; eb_s[t] = eb[t];
                  m_s[t] = -3.4e38f;  s_s[t] = 0.f; }
    float2 acc = make_float2(0.f, 0.f);
    const int hp = (2 * t) / D;     // head of this thread's output pair
    __syncthreads();

    for (int base = 0; base < deg; base += C) {
        const int cl = min(C, deg - base);
        if (t < cl) {
            srcs[t] = srcA[s0 + base + t];
            eas[t]  = ea[eidA[s0 + base + t]];
        }
        __syncthreads();
        // logits for this chunk: thread item = p*NH + h ; bf16 KR row
        for (int item = t; item < cl * NH; item += 256) {
            const int p = item / NH, h = item - p * NH;
            const unsigned int* kr =
                (const unsigned int*)(KR + (size_t)srcs[p] * HD + h * D);
            const float* q = q_s + h * D;
            float d0 = 0.f;
            #pragma unroll
            for (int dd = 0; dd < D / 2; ++dd) {
                const unsigned int w = kr[dd];
                d0 = fmaf(q[2 * dd],     bf_lo(w), d0);
                d0 = fmaf(q[2 * dd + 1], bf_hi(w), d0);
            }
            ls[p][h] = d0 * scale * prel_s[h] + eas[p] * ew_s[h] + eb_s[h];
        }
        __syncthreads();
        // per-head online softmax: 16 lanes per head (lane-aligned groups)
        if (t < NH * 16) {
            const int h = t >> 4, sub = t & 15;
            float cm = -3.4e38f;
            for (int p = sub; p < cl; p += 16) cm = fmaxf(cm, ls[p][h]);
            #pragma unroll
            for (int off = 8; off; off >>= 1) cm = fmaxf(cm, __shfl_xor(cm, off));
            const float nm = fmaxf(m_s[h], cm);
            float cs = 0.f;
            for (int p = sub; p < cl; p += 16) {
                float w = expf(ls[p][h] - nm);
                ls[p][h] = w;
                cs += w;
            }
            #pragma unroll
            for (int off = 8; off; off >>= 1) cs += __shfl_xor(cs, off);
            if (sub == 0) {
                const float r = expf(m_s[h] - nm);
                s_s[h] = s_s[h] * r + cs;
                m_s[h] = nm;
                rexp_s[h] = r;
            }
        }
        __syncthreads();
        // accumulate VR bf16 pairs weighted by exp-logits (coalesced dword/lane)
        if (t < PAIRS) {
            const float r = rexp_s[hp];
            acc.x *= r; acc.y *= r;
            for (int p = 0; p < cl; ++p) {
                const unsigned int w =
                    *(const unsigned int*)(VR + (size_t)srcs[p] * HD + 2 * t);
                const float wgt = ls[p][hp];
                acc.x = fmaf(wgt, bf_lo(w), acc.x);
                acc.y = fmaf(wgt, bf_hi(w), acc.y);
            }
        }
        __syncthreads();
    }
    if (t < PAIRS) {
        const float inv = 1.f / (s_s[hp] + 1e-16f);
        *reinterpret_cast<float2*>(out + (size_t)dst * HD + 2 * t) =
            make_float2(gelu_f(acc.x * inv), gelu_f(acc.y * inv));
    }
}

// ---------------------------------------------------------------- CSR build
__global__ void count_kernel(const int* __restrict__ ei, int* __restrict__ cnt)
{
    int e = blockIdx.x * blockDim.x + threadIdx.x;
    if (e < N_EDGES) atomicAdd(&cnt[ei[N_EDGES + e]], 1);
}

__global__ void scatter_kernel(const int* __restrict__ ei, int* __restrict__ cursor,
                               int* __restrict__ srcA, int* __restrict__ eidA)
{
    int e = blockIdx.x * blockDim.x + threadIdx.x;
    if (e >= N_EDGES) return;
    int dst = ei[N_EDGES + e];
    int pos = atomicAdd(&cursor[dst], 1);
    srcA[pos] = ei[e];
    eidA[pos] = e;
}

// single-block exclusive scan of n ints -> rp[0..n], also copies to cursor
__global__ void exscan_kernel(const int* __restrict__ cnt, int* __restrict__ rp,
                              int* __restrict__ cursor, int n)
{
    __shared__ int buf[1024];
    __shared__ int carry;
    int t = threadIdx.x;
    if (t == 0) carry = 0;
    __syncthreads();
    for (int base = 0; base < n; base += 1024) {
        int v = (base + t < n) ? cnt[base + t] : 0;
        buf[t] = v;
        __syncthreads();
        for (int off = 1; off < 1024; off <<= 1) {
            int x = (t >= off) ? buf[t - off] : 0;
            __syncthreads();
            buf[t] += x;
            __syncthreads();
        }
        int excl = buf[t] - v + carry;
        if (base + t < n) { rp[base + t] = excl; cursor[base + t] = excl; }
        int total = buf[1023];
        __syncthreads();
        if (t == 0) carry += total;
        __syncthreads();
    }
    if (t == 0) rp[n] = carry;
}

// ---------------------------------------------------------------- batchnorm
__global__ void colstat_kernel(const float* __restrict__ X, float* __restrict__ sums,
                               int M, int N)
{
    __shared__ float ls[256], lq[256];
    int c = blockIdx.x * 64 + (threadIdx.x & 63);
    int rl = threadIdx.x >> 6;
    float s = 0.f, q = 0.f;
    for (int r = blockIdx.y * 4 + rl; r < M; r += gridDim.y * 4) {
        float v = X[(size_t)r * N + c];
        s += v; q = fmaf(v, v, q);
    }
    ls[threadIdx.x] = s; lq[threadIdx.x] = q;
    __syncthreads();
    if (rl == 0) {
        s = ls[threadIdx.x] + ls[threadIdx.x + 64] + ls[threadIdx.x + 128] + ls[threadIdx.x + 192];
        q = lq[threadIdx.x] + lq[threadIdx.x + 64] + lq[threadIdx.x + 128] + lq[threadIdx.x + 192];
        atomicAdd(&sums[c], s);
        atomicAdd(&sums[N + c], q);
    }
}

__global__ void bn_kernel(float* __restrict__ X, const float* __restrict__ sums,
                          const float* __restrict__ g, const float* __restrict__ b,
                          int M, int N)
{
    int tid = blockIdx.x * blockDim.x + threadIdx.x;
    if (tid >= M * N) return;
    int c = tid % N;
    float mu = sums[c] / (float)M;
    float var = sums[N + c] / (float)M - mu * mu;
    X[tid] = (X[tid] - mu) * rsqrtf(var + 1e-5f) * g[c] + b[c];
}

// ---------------------------------------------------------------- output epilogues
__global__ void rownorm_kernel(const float* __restrict__ X, float* __restrict__ out)
{
    int row = blockIdx.x;
    int l = threadIdx.x;   // 64 threads
    const float* x = X + (size_t)row * 128;
    float v0 = x[l], v1 = x[l + 64];
    float ss = v0 * v0 + v1 * v1;
    #pragma unroll
    for (int off = 32; off; off >>= 1) ss += __shfl_xor(ss, off);
    float inv = rsqrtf(ss + 1e-12f);
    out[(size_t)row * 128 + l] = v0 * inv;
    out[(size_t)row * 128 + l + 64] = v1 * inv;
}

__global__ void rowsoftmax_kernel(const float* __restrict__ X, float* __restrict__ out)
{
    int row = blockIdx.x;
    int l = threadIdx.x;   // 64 threads, 129 columns
    const float* x = X + (size_t)row * 129;
    float v0 = x[l], v1 = x[l + 64];
    float v2 = (l == 0) ? x[128] : -3.4e38f;
    float m = fmaxf(fmaxf(v0, v1), v2);
    #pragma unroll
    for (int off = 32; off; off >>= 1) m = fmaxf(m, __shfl_xor(m, off));
    float e0 = expf(v0 - m), e1 = expf(v1 - m);
    float e2 = (l == 0) ? expf(v2 - m) : 0.f;
    float s = e0 + e1 + e2;
    #pragma unroll
    for (int off = 32; off; off >>= 1) s += __shfl_xor(s, off);
    float inv = 1.f / s;
    out[(size_t)row * 129 + l] = e0 * inv;
    out[(size_t)row * 129 + l + 64] = e1 * inv;
    if (l == 0) out[(size_t)row * 129 + 128] = e2 * inv;
}

// ---------------------------------------------------------------- host-side plumbing
static inline void launch_gemm(const float* A, const float* W, const float* bias, float* C,
                               int M, int N, int K, int act, hipStream_t s)
{
    dim3 grid((N + 63) / 64, (M + 127) / 128);
    if (act) gemm_kernel<1, float><<<grid, 256, 0, s>>>(A, W, bias, C, M, N, K);
    else     gemm_kernel<0, float><<<grid, 256, 0, s>>>(A, W, bias, C, M, N, K);
}
static inline void launch_gemm_bf16(const float* A, const float* W, const float* bias,
                                    __hip_bfloat16* C, int M, int N, int K, hipStream_t s)
{
    dim3 grid((N + 63) / 64, (M + 127) / 128);
    gemm_kernel<0, __hip_bfloat16><<<grid, 256, 0, s>>>(A, W, bias, C, M, N, K);
}

struct LayerParams {
    const float *kw, *kb, *qw, *qb, *vw, *vb, *arel, *mrel, *prel, *ew, *eb, *alw, *alb;
};

struct CsrRel { const int* rp; const int* src; const int* eid; };

template<int D>
static void run_layer(const LayerParams& P, int fin,
                      const float* xa, const float* xu,
                      float* B3, float* B4, float* B5, float* B6, float* B7,
                      float* WFK, float* WFV,
                      float* ya, float* yu,
                      const float* ea_au, const float* ea_ua,
                      const CsrRel& au, const CsrRel& ua, hipStream_t s)
{
    const int HD = NH * D;
    const float scale = 1.0f / sqrtf((float)D);
    const int gFW = ((fin + 1) * HD + 255) / 256;
    __hip_bfloat16* KRb = (__hip_bfloat16*)B3;
    __hip_bfloat16* VRb = (__hip_bfloat16*)B4;

    // ---- relation ant->user (r=0): k/v from ant (type 0), q from user
    fuse_w_kernel<<<gFW, 256, 0, s>>>(P.kw, P.kb, P.arel, WFK, fin, D, HD);
    fuse_w_kernel<<<gFW, 256, 0, s>>>(P.vw, P.vb, P.mrel, WFV, fin, D, HD);
    launch_gemm_bf16(xa, WFK, WFK + (size_t)fin * HD, KRb, N_NODES, HD, fin, s);      // kr_a
    launch_gemm_bf16(xa, WFV, WFV + (size_t)fin * HD, VRb, N_NODES, HD, fin, s);      // vr_a
    launch_gemm(xu, P.qw + (size_t)fin * HD, P.qb + HD, B5, N_NODES, HD, fin, 0, s);  // q_u
    edge_fused_kernel<D><<<N_NODES, 256, 0, s>>>(
        B5, KRb, VRb, au.rp, au.src, au.eid, ea_au,
        P.prel, P.ew, P.eb, B6, scale);                                               // B6 = gelu(agg_u)

    // ---- relation user->ant (r=1): k/v from user (type 1), q from ant
    fuse_w_kernel<<<gFW, 256, 0, s>>>(P.kw + (size_t)fin * HD, P.kb + HD,
                                      P.arel + (size_t)NH * D * D, WFK, fin, D, HD);
    fuse_w_kernel<<<gFW, 256, 0, s>>>(P.vw + (size_t)fin * HD, P.vb + HD,
                                      P.mrel + (size_t)NH * D * D, WFV, fin, D, HD);
    launch_gemm_bf16(xu, WFK, WFK + (size_t)fin * HD, KRb, N_NODES, HD, fin, s);      // kr_u
    launch_gemm_bf16(xu, WFV, WFV + (size_t)fin * HD, VRb, N_NODES, HD, fin, s);      // vr_u
    launch_gemm(xa, P.qw, P.qb, B5, N_NODES, HD, fin, 0, s);                          // q_a
    edge_fused_kernel<D><<<N_NODES, 256, 0, s>>>(
        B5, KRb, VRb, ua.rp, ua.src, ua.eid, ea_ua,
        P.prel + NH, P.ew + NH, P.eb + NH, B7, scale);                                // B7 = gelu(agg_a)

    // ---- per-type output linear (gelu applied in edge kernel), elu-out
    launch_gemm(B7, P.alw, P.alb, ya, N_NODES, HD, HD, 1, s);                          // out_a
    launch_gemm(B6, P.alw + (size_t)HD * HD, P.alb + HD, yu, N_NODES, HD, HD, 1, s);   // out_u
}

extern "C" void kernel_launch(void* const* d_in, const int* in_sizes, int n_in,
                              void* d_out, int out_size, void* d_ws, size_t ws_size,
                              hipStream_t stream)
{
    // ---- inputs
    const float* x_ant  = (const float*)d_in[0];
    const float* x_user = (const float*)d_in[1];
    const float* ea_au  = (const float*)d_in[2];
    const float* ea_ua  = (const float*)d_in[3];
    LayerParams L1 = {
        (const float*)d_in[4],  (const float*)d_in[5],  (const float*)d_in[6],
        (const float*)d_in[7],  (const float*)d_in[8],  (const float*)d_in[9],
        (const float*)d_in[10], (const float*)d_in[11], (const float*)d_in[12],
        (const float*)d_in[13], (const float*)d_in[14], (const float*)d_in[15],
        (const float*)d_in[16]
    };
    LayerParams L2 = {
        (const float*)d_in[17], (const float*)d_in[18], (const float*)d_in[19],
        (const float*)d_in[20], (const float*)d_in[21], (const float*)d_in[22],
        (const float*)d_in[23], (const float*)d_in[24], (const float*)d_in[25],
        (const float*)d_in[26], (const float*)d_in[27], (const float*)d_in[28],
        (const float*)d_in[29]
    };
    const float* lin1_w  = (const float*)d_in[30];
    const float* lin1_b  = (const float*)d_in[31];
    const float* bn_g    = (const float*)d_in[32];
    const float* bn_b    = (const float*)d_in[33];
    const float* lin2_wa = (const float*)d_in[34];
    const float* lin2_ba = (const float*)d_in[35];
    const float* lin2_wu = (const float*)d_in[36];
    const float* lin2_bu = (const float*)d_in[37];
    const int*   ei_au   = (const int*)d_in[38];
    const int*   ei_ua   = (const int*)d_in[39];

    // ---- workspace arena (floats)
    float* F = (float*)d_ws;
    const size_t SLOT = (size_t)N_NODES * 320;
    float* B0 = F + 0 * SLOT;
    float* B1 = F + 1 * SLOT;
    float* B2 = F + 2 * SLOT;
    float* B3 = F + 3 * SLOT;
    float* B4 = F + 4 * SLOT;
    float* B5 = F + 5 * SLOT;
    float* B6 = F + 6 * SLOT;
    float* B7 = F + 7 * SLOT;
    float* STATS = F + 8 * SLOT;                       // 1024 (sum512 + sumsq512)
    int* I = (int*)(STATS + 1024);
    int* rp_au  = I;
    int* rp_ua  = rp_au + N_NODES + 1;
    int* src_au = rp_ua + N_NODES + 1;
    int* eid_au = src_au + N_EDGES;
    int* src_ua = eid_au + N_EDGES;
    int* eid_ua = src_ua + N_EDGES;
    int* cursor = eid_ua + N_EDGES;
    int* counts = cursor + N_NODES;
    float* WFK = (float*)(counts + N_NODES);           // (fin+1)*HD <= 161*320
    float* WFV = WFK + 161 * 320;

    const int gE = (N_EDGES + 255) / 256;

    // ---- CSR build (per relation, reused by both layers)
    hipMemsetAsync(counts, 0, N_NODES * sizeof(int), stream);
    count_kernel<<<gE, 256, 0, stream>>>(ei_au, counts);
    exscan_kernel<<<1, 1024, 0, stream>>>(counts, rp_au, cursor, N_NODES);
    scatter_kernel<<<gE, 256, 0, stream>>>(ei_au, cursor, src_au, eid_au);

    hipMemsetAsync(counts, 0, N_NODES * sizeof(int), stream);
    count_kernel<<<gE, 256, 0, stream>>>(ei_ua, counts);
    exscan_kernel<<<1, 1024, 0, stream>>>(counts, rp_ua, cursor, N_NODES);
    scatter_kernel<<<gE, 256, 0, stream>>>(ei_ua, cursor, src_ua, eid_ua);

    CsrRel au = { rp_au, src_au, eid_au };
    CsrRel ua = { rp_ua, src_ua, eid_ua };

    // ---- HGT layer 1: fin=128, D=16 -> outputs [N,160] in B0 (ant), B1 (user), elu applied
    run_layer<16>(L1, 128, x_ant, x_user, B3, B4, B5, B6, B7, WFK, WFV, B0, B1,
                  ea_au, ea_ua, au, ua, stream);

    // ---- HGT layer 2: fin=160, D=32 -> outputs [N,320] in B0, B1, elu applied
    run_layer<32>(L2, 160, B0, B1, B3, B4, B5, B6, B7, WFK, WFV, B0, B1,
                  ea_au, ea_ua, au, ua, stream);

    // ---- lin1 + elu:  [N,320] @ [320,512]
    float* L1A = B2;   // spans B2..B3 (N*512 floats)
    float* L1U = B4;   // spans B4..B5
    launch_gemm(B0, lin1_w, lin1_b, L1A, N_NODES, 512, 320, 1, stream);
    launch_gemm(B1, lin1_w + (size_t)320 * 512, lin1_b + 512, L1U, N_NODES, 512, 320, 1, stream);

    // ---- batchnorm (population stats over rows), in-place
    hipMemsetAsync(STATS, 0, 1024 * sizeof(float), stream);
    colstat_kernel<<<dim3(8, 32), 256, 0, stream>>>(L1A, STATS, N_NODES, 512);
    bn_kernel<<<(N_NODES * 512 + 255) / 256, 256, 0, stream>>>(L1A, STATS, bn_g, bn_b,
                                                               N_NODES, 512);
    hipMemsetAsync(STATS, 0, 1024 * sizeof(float), stream);
    colstat_kernel<<<dim3(8, 32), 256, 0, stream>>>(L1U, STATS, N_NODES, 512);
    bn_kernel<<<(N_NODES * 512 + 255) / 256, 256, 0, stream>>>(L1U, STATS, bn_g + 512,
                                                               bn_b + 512, N_NODES, 512);

    // ---- lin2 + output epilogues
    float* OUTA = B6;  // [N,128]
    float* OUTU = B7;  // [N,129]
    launch_gemm(L1A, lin2_wa, lin2_ba, OUTA, N_NODES, 128, 512, 0, stream);
    rownorm_kernel<<<N_NODES, 64, 0, stream>>>(OUTA, (float*)d_out);
    launch_gemm(L1U, lin2_wu, lin2_bu, OUTU, N_NODES, 129, 512, 0, stream);
    rowsoftmax_kernel<<<N_NODES, 64, 0, stream>>>(
        OUTU, (float*)d_out + (size_t)N_NODES * 128);
}

// Round 6
// 1380.982 us; speedup vs baseline: 7.7944x; 1.3486x over previous
//
#include <hip/hip_runtime.h>
#include <hip/hip_bf16.h>
#include <math.h>

#define N_NODES 20000
#define N_EDGES 400000
#define NH 10

typedef __attribute__((ext_vector_type(8))) short short8v;
typedef __attribute__((ext_vector_type(4))) float f32x4;

// ---------------------------------------------------------------- helpers
__device__ __forceinline__ float gelu_f(float x) {
    float x3 = x * x * x;
    return 0.5f * x * (1.0f + tanhf(0.7978845608028654f * (x + 0.044715f * x3)));
}
__device__ __forceinline__ float elu_f(float x) {
    return x > 0.0f ? x : (expf(x) - 1.0f);
}
__device__ __forceinline__ float bf_lo(unsigned int w) {
    return __uint_as_float(w << 16);
}
__device__ __forceinline__ float bf_hi(unsigned int w) {
    return __uint_as_float(w & 0xffff0000u);
}
__device__ __forceinline__ unsigned short f2b(float x) {   // RNE f32->bf16 bits
    unsigned int u = __float_as_uint(x);
    return (unsigned short)((u + 0x7fffu + ((u >> 16) & 1u)) >> 16);
}

// ---------------------------------------------------------------- MFMA GEMM
// C[M,N] = act(A[M,K] @ W[K,N] + bias[N]), W given TRANSPOSED as WT[N][K] bf16.
// A is f32, converted to bf16 during LDS staging; accumulate fp32 via
// mfma_f32_16x16x32_bf16. BM=128, BN=64, BK=32; 256 thr = 4 waves, each wave
// computes 64x32 (4x2 fragments of 16x16). K must be a multiple of 32.
// LDS pitch 40 bf16 (80B): 8 consecutive rows tile all 32 banks -> 2-way
// aliasing on ds_read_b128 (free, m136).
template<int ACT, typename OUT>
__global__ __launch_bounds__(256) void mfma_gemm_kernel(
    const float* __restrict__ A, const __hip_bfloat16* __restrict__ WT,
    const float* __restrict__ bias, OUT* __restrict__ C,
    int M, int N, int K)
{
    constexpr int PITCH = 40;
    __shared__ __align__(16) unsigned short As[128 * PITCH];
    __shared__ __align__(16) unsigned short Bs[64 * PITCH];
    const int tid = threadIdx.x;
    const int m0 = blockIdx.y * 128, n0 = blockIdx.x * 64;
    const int w = tid >> 6, l = tid & 63;
    const int wr = w >> 1, wc = w & 1;          // 2x2 wave grid
    const int lr = l & 15, lk = l >> 4;         // fragment row/col, k-block

    const int arow = tid >> 1, akb = (tid & 1) * 16;  // A staging: 2 thr/row
    const int brow = tid >> 2, bkb = (tid & 3) * 8;   // B staging: 4 thr/row
    const bool ainb = (m0 + arow) < M;
    const bool binb = (n0 + brow) < N;

    f32x4 acc[4][2] = {};
    for (int k0 = 0; k0 < K; k0 += 32) {
        // stage A tile (f32 -> bf16)
        {
            const float* ap = A + (size_t)(m0 + arow) * K + k0 + akb;
            #pragma unroll
            for (int j = 0; j < 4; ++j) {
                float4 v = ainb ? *reinterpret_cast<const float4*>(ap + j * 4)
                                : make_float4(0.f, 0.f, 0.f, 0.f);
                ushort4 b;
                b.x = f2b(v.x); b.y = f2b(v.y); b.z = f2b(v.z); b.w = f2b(v.w);
                *reinterpret_cast<ushort4*>(&As[arow * PITCH + akb + j * 4]) = b;
            }
        }
        // stage B tile (bf16 copy of WT rows)
        {
            int4 v = binb ? *reinterpret_cast<const int4*>(
                                WT + (size_t)(n0 + brow) * K + k0 + bkb)
                          : make_int4(0, 0, 0, 0);
            *reinterpret_cast<int4*>(&Bs[brow * PITCH + bkb]) = v;
        }
        __syncthreads();
        short8v a[4], b[2];
        #pragma unroll
        for (int mi = 0; mi < 4; ++mi)
            a[mi] = *reinterpret_cast<const short8v*>(
                &As[(wr * 64 + mi * 16 + lr) * PITCH + lk * 8]);
        #pragma unroll
        for (int ni = 0; ni < 2; ++ni)
            b[ni] = *reinterpret_cast<const short8v*>(
                &Bs[(wc * 32 + ni * 16 + lr) * PITCH + lk * 8]);
        #pragma unroll
        for (int mi = 0; mi < 4; ++mi)
            #pragma unroll
            for (int ni = 0; ni < 2; ++ni)
                acc[mi][ni] = __builtin_amdgcn_mfma_f32_16x16x32_bf16(
                    a[mi], b[ni], acc[mi][ni], 0, 0, 0);
        __syncthreads();
    }
    // epilogue: D frag -> C ; col=lane&15, row=(lane>>4)*4+reg (m89-verified)
    #pragma unroll
    for (int ni = 0; ni < 2; ++ni) {
        const int col = n0 + wc * 32 + ni * 16 + lr;
        if (col >= N) continue;
        const float bv = bias[col];
        #pragma unroll
        for (int mi = 0; mi < 4; ++mi) {
            const int rb = m0 + wr * 64 + mi * 16 + lk * 4;
            #pragma unroll
            for (int j = 0; j < 4; ++j) {
                const int m = rb + j;
                if (m >= M) continue;
                float v = acc[mi][ni][j] + bv;
                if (ACT == 1) v = elu_f(v);
                if constexpr (sizeof(OUT) == 2)
                    C[(size_t)m * N + col] = __float2bfloat16(v);
                else
                    C[(size_t)m * N + col] = v;
            }
        }
    }
}

// ---------------------------------------------------------------- weight transpose+convert
// in f32 [K][N] -> out bf16 [N][K]
__global__ void transpose_w_kernel(const float* __restrict__ in,
                                   __hip_bfloat16* __restrict__ out, int K, int N)
{
    __shared__ float tile[32][33];
    const int nb = blockIdx.x * 32, kb = blockIdx.y * 32;
    const int tx = threadIdx.x & 31, ty = threadIdx.x >> 5;   // 32x8
    for (int j = ty; j < 32; j += 8) {
        int k = kb + j, n = nb + tx;
        tile[j][tx] = (k < K && n < N) ? in[(size_t)k * N + n] : 0.f;
    }
    __syncthreads();
    for (int j = ty; j < 32; j += 8) {
        int n = nb + j, k = kb + tx;
        if (n < N && k < K) out[(size_t)n * K + k] = __float2bfloat16(tile[tx][j]);
    }
}

// ---------------------------------------------------------------- fused K/V weight precompute
// WfT[col][f] = bf16( sum_d KW[f][h*D+d] * REL[h][d][e] ),  col=h*D+e; biasv[col]
// from kb. Folds the per-node relation transform into a transposed projection weight.
__global__ void fuse_w_kernel(const float* __restrict__ KW, const float* __restrict__ kb,
                              const float* __restrict__ REL,
                              __hip_bfloat16* __restrict__ WfT, float* __restrict__ biasv,
                              int fin, int D, int HD)
{
    const int total = (fin + 1) * HD;
    int tid = blockIdx.x * blockDim.x + threadIdx.x;
    if (tid >= total) return;
    const int col = tid % HD, f = tid / HD;
    const int h = col / D, e = col - h * D;
    const float* src = (f < fin) ? KW + (size_t)f * HD + h * D : kb + h * D;
    const float* r = REL + (size_t)h * D * D + e;   // stride D over d
    float acc = 0.f;
    for (int d = 0; d < D; ++d) acc = fmaf(src[d], r[(size_t)d * D], acc);
    if (f < fin) WfT[(size_t)col * fin + f] = __float2bfloat16(acc);
    else         biasv[col] = acc;
}

// ---------------------------------------------------------------- fused edge pipeline
// One block per dst node (CSR order): logits, chunked online segment softmax
// (16 lanes/head), weighted aggregation, gelu. Q[dst] fp32 in LDS; KR/VR bf16.
template<int D>
__global__ __launch_bounds__(256) void edge_fused_kernel(
    const float* __restrict__ Q,                // [N, HD] fp32
    const __hip_bfloat16* __restrict__ KR,      // [N, HD] bf16
    const __hip_bfloat16* __restrict__ VR,      // [N, HD] bf16
    const int* __restrict__ rp, const int* __restrict__ srcA,
    const int* __restrict__ eidA, const float* __restrict__ ea,
    const float* __restrict__ prel, const float* __restrict__ ew,
    const float* __restrict__ eb,               // [NH], relation-offset
    float* __restrict__ out,                    // [N, HD], gelu applied
    float scale)
{
    constexpr int HD = NH * D;
    constexpr int PAIRS = HD / 2;
    constexpr int C = 64;
    __shared__ float q_s[HD];
    __shared__ float ls[C][NH];
    __shared__ int   srcs[C];
    __shared__ float eas[C];
    __shared__ float prel_s[NH], ew_s[NH], eb_s[NH];
    __shared__ float m_s[NH], s_s[NH], rexp_s[NH];

    const int dst = blockIdx.x;
    const int t = threadIdx.x;
    const int s0 = rp[dst], s1 = rp[dst + 1];
    const int deg = s1 - s0;

    for (int i = t; i < HD; i += 256) q_s[i] = Q[(size_t)dst * HD + i];
    if (t < NH) { prel_s[t] = prel[t]; ew_s[t] = ew[t]; eb_s[t] = eb[t];
                  m_s[t] = -3.4e38f;  s_s[t] = 0.f; }
    float2 acc = make_float2(0.f, 0.f);
    const int hp = (2 * t) / D;
    __syncthreads();

    for (int base = 0; base < deg; base += C) {
        const int cl = min(C, deg - base);
        if (t < cl) {
            srcs[t] = srcA[s0 + base + t];
            eas[t]  = ea[eidA[s0 + base + t]];
        }
        __syncthreads();
        for (int item = t; item < cl * NH; item += 256) {
            const int p = item / NH, h = item - p * NH;
            const unsigned int* kr =
                (const unsigned int*)(KR + (size_t)srcs[p] * HD + h * D);
            const float* q = q_s + h * D;
            float d0 = 0.f;
            #pragma unroll
            for (int dd = 0; dd < D / 2; ++dd) {
                const unsigned int w = kr[dd];
                d0 = fmaf(q[2 * dd],     bf_lo(w), d0);
                d0 = fmaf(q[2 * dd + 1], bf_hi(w), d0);
            }
            ls[p][h] = d0 * scale * prel_s[h] + eas[p] * ew_s[h] + eb_s[h];
        }
        __syncthreads();
        if (t < NH * 16) {
            const int h = t >> 4, sub = t & 15;
            float cm = -3.4e38f;
            for (int p = sub; p < cl; p += 16) cm = fmaxf(cm, ls[p][h]);
            #pragma unroll
            for (int off = 8; off; off >>= 1) cm = fmaxf(cm, __shfl_xor(cm, off));
            const float nm = fmaxf(m_s[h], cm);
            float cs = 0.f;
            for (int p = sub; p < cl; p += 16) {
                float w = expf(ls[p][h] - nm);
                ls[p][h] = w;
                cs += w;
            }
            #pragma unroll
            for (int off = 8; off; off >>= 1) cs += __shfl_xor(cs, off);
            if (sub == 0) {
                const float r = expf(m_s[h] - nm);
                s_s[h] = s_s[h] * r + cs;
                m_s[h] = nm;
                rexp_s[h] = r;
            }
        }
        __syncthreads();
        if (t < PAIRS) {
            const float r = rexp_s[hp];
            acc.x *= r; acc.y *= r;
            for (int p = 0; p < cl; ++p) {
                const unsigned int w =
                    *(const unsigned int*)(VR + (size_t)srcs[p] * HD + 2 * t);
                const float wgt = ls[p][hp];
                acc.x = fmaf(wgt, bf_lo(w), acc.x);
                acc.y = fmaf(wgt, bf_hi(w), acc.y);
            }
        }
        __syncthreads();
    }
    if (t < PAIRS) {
        const float inv = 1.f / (s_s[hp] + 1e-16f);
        *reinterpret_cast<float2*>(out + (size_t)dst * HD + 2 * t) =
            make_float2(gelu_f(acc.x * inv), gelu_f(acc.y * inv));
    }
}

// ---------------------------------------------------------------- CSR build
__global__ void count_kernel(const int* __restrict__ ei, int* __restrict__ cnt)
{
    int e = blockIdx.x * blockDim.x + threadIdx.x;
    if (e < N_EDGES) atomicAdd(&cnt[ei[N_EDGES + e]], 1);
}

__global__ void scatter_kernel(const int* __restrict__ ei, int* __restrict__ cursor,
                               int* __restrict__ srcA, int* __restrict__ eidA)
{
    int e = blockIdx.x * blockDim.x + threadIdx.x;
    if (e >= N_EDGES) return;
    int dst = ei[N_EDGES + e];
    int pos = atomicAdd(&cursor[dst], 1);
    srcA[pos] = ei[e];
    eidA[pos] = e;
}

__global__ void exscan_kernel(const int* __restrict__ cnt, int* __restrict__ rp,
                              int* __restrict__ cursor, int n)
{
    __shared__ int buf[1024];
    __shared__ int carry;
    int t = threadIdx.x;
    if (t == 0) carry = 0;
    __syncthreads();
    for (int base = 0; base < n; base += 1024) {
        int v = (base + t < n) ? cnt[base + t] : 0;
        buf[t] = v;
        __syncthreads();
        for (int off = 1; off < 1024; off <<= 1) {
            int x = (t >= off) ? buf[t - off] : 0;
            __syncthreads();
            buf[t] += x;
            __syncthreads();
        }
        int excl = buf[t] - v + carry;
        if (base + t < n) { rp[base + t] = excl; cursor[base + t] = excl; }
        int total = buf[1023];
        __syncthreads();
        if (t == 0) carry += total;
        __syncthreads();
    }
    if (t == 0) rp[n] = carry;
}

// ---------------------------------------------------------------- batchnorm
__global__ void colstat_kernel(const float* __restrict__ X, float* __restrict__ sums,
                               int M, int N)
{
    __shared__ float ls[256], lq[256];
    int c = blockIdx.x * 64 + (threadIdx.x & 63);
    int rl = threadIdx.x >> 6;
    float s = 0.f, q = 0.f;
    for (int r = blockIdx.y * 4 + rl; r < M; r += gridDim.y * 4) {
        float v = X[(size_t)r * N + c];
        s += v; q = fmaf(v, v, q);
    }
    ls[threadIdx.x] = s; lq[threadIdx.x] = q;
    __syncthreads();
    if (rl == 0) {
        s = ls[threadIdx.x] + ls[threadIdx.x + 64] + ls[threadIdx.x + 128] + ls[threadIdx.x + 192];
        q = lq[threadIdx.x] + lq[threadIdx.x + 64] + lq[threadIdx.x + 128] + lq[threadIdx.x + 192];
        atomicAdd(&sums[c], s);
        atomicAdd(&sums[N + c], q);
    }
}

__global__ void bn_kernel(float* __restrict__ X, const float* __restrict__ sums,
                          const float* __restrict__ g, const float* __restrict__ b,
                          int M, int N)
{
    int tid = blockIdx.x * blockDim.x + threadIdx.x;
    if (tid >= M * N) return;
    int c = tid % N;
    float mu = sums[c] / (float)M;
    float var = sums[N + c] / (float)M - mu * mu;
    X[tid] = (X[tid] - mu) * rsqrtf(var + 1e-5f) * g[c] + b[c];
}

// ---------------------------------------------------------------- output epilogues
__global__ void rownorm_kernel(const float* __restrict__ X, float* __restrict__ out)
{
    int row = blockIdx.x;
    int l = threadIdx.x;   // 64 threads
    const float* x = X + (size_t)row * 128;
    float v0 = x[l], v1 = x[l + 64];
    float ss = v0 * v0 + v1 * v1;
    #pragma unroll
    for (int off = 32; off; off >>= 1) ss += __shfl_xor(ss, off);
    float inv = rsqrtf(ss + 1e-12f);
    out[(size_t)row * 128 + l] = v0 * inv;
    out[(size_t)row * 128 + l + 64] = v1 * inv;
}

__global__ void rowsoftmax_kernel(const float* __restrict__ X, float* __restrict__ out)
{
    int row = blockIdx.x;
    int l = threadIdx.x;   // 64 threads, 129 columns
    const float* x = X + (size_t)row * 129;
    float v0 = x[l], v1 = x[l + 64];
    float v2 = (l == 0) ? x[128] : -3.4e38f;
    float m = fmaxf(fmaxf(v0, v1), v2);
    #pragma unroll
    for (int off = 32; off; off >>= 1) m = fmaxf(m, __shfl_xor(m, off));
    float e0 = expf(v0 - m), e1 = expf(v1 - m);
    float e2 = (l == 0) ? expf(v2 - m) : 0.f;
    float s = e0 + e1 + e2;
    #pragma unroll
    for (int off = 32; off; off >>= 1) s += __shfl_xor(s, off);
    float inv = 1.f / s;
    out[(size_t)row * 129 + l] = e0 * inv;
    out[(size_t)row * 129 + l + 64] = e1 * inv;
    if (l == 0) out[(size_t)row * 129 + 128] = e2 * inv;
}

// ---------------------------------------------------------------- host-side plumbing
template<typename OUT>
static inline void launch_mfma(const float* A, const __hip_bfloat16* WT,
                               const float* bias, OUT* C,
                               int M, int N, int K, int act, hipStream_t s)
{
    dim3 grid((N + 63) / 64, (M + 127) / 128);
    if (act) mfma_gemm_kernel<1, OUT><<<grid, 256, 0, s>>>(A, WT, bias, C, M, N, K);
    else     mfma_gemm_kernel<0, OUT><<<grid, 256, 0, s>>>(A, WT, bias, C, M, N, K);
}
static inline void launch_transpose(const float* in, __hip_bfloat16* out,
                                    int K, int N, hipStream_t s)
{
    dim3 grid((N + 31) / 32, (K + 31) / 32);
    transpose_w_kernel<<<grid, 256, 0, s>>>(in, out, K, N);
}

struct LayerParams {
    const float *kw, *kb, *qw, *qb, *vw, *vb, *arel, *mrel, *prel, *ew, *eb, *alw, *alb;
};

struct CsrRel { const int* rp; const int* src; const int* eid; };

template<int D>
static void run_layer(const LayerParams& P, int fin,
                      const float* xa, const float* xu,
                      float* B5, float* B6, float* B7,
                      __hip_bfloat16* KRb, __hip_bfloat16* VRb,
                      __hip_bfloat16* WT1, __hip_bfloat16* WT2, __hip_bfloat16* WT3,
                      float* BIAS1, float* BIAS2,
                      float* ya, float* yu,
                      const float* ea_au, const float* ea_ua,
                      const CsrRel& au, const CsrRel& ua, hipStream_t s)
{
    const int HD = NH * D;
    const float scale = 1.0f / sqrtf((float)D);
    const int gFW = ((fin + 1) * HD + 255) / 256;

    // ---- relation ant->user (r=0): k/v from ant (type 0), q from user (type 1)
    fuse_w_kernel<<<gFW, 256, 0, s>>>(P.kw, P.kb, P.arel, WT1, BIAS1, fin, D, HD);
    fuse_w_kernel<<<gFW, 256, 0, s>>>(P.vw, P.vb, P.mrel, WT2, BIAS2, fin, D, HD);
    launch_transpose(P.qw + (size_t)fin * HD, WT3, fin, HD, s);
    launch_mfma(xa, WT1, BIAS1, KRb, N_NODES, HD, fin, 0, s);            // kr_a (bf16)
    launch_mfma(xa, WT2, BIAS2, VRb, N_NODES, HD, fin, 0, s);            // vr_a (bf16)
    launch_mfma(xu, WT3, P.qb + HD, B5, N_NODES, HD, fin, 0, s);         // q_u (f32)
    edge_fused_kernel<D><<<N_NODES, 256, 0, s>>>(
        B5, KRb, VRb, au.rp, au.src, au.eid, ea_au,
        P.prel, P.ew, P.eb, B6, scale);                                  // B6 = gelu(agg_u)

    // ---- relation user->ant (r=1): k/v from user (type 1), q from ant (type 0)
    fuse_w_kernel<<<gFW, 256, 0, s>>>(P.kw + (size_t)fin * HD, P.kb + HD,
                                      P.arel + (size_t)NH * D * D, WT1, BIAS1, fin, D, HD);
    fuse_w_kernel<<<gFW, 256, 0, s>>>(P.vw + (size_t)fin * HD, P.vb + HD,
                                      P.mrel + (size_t)NH * D * D, WT2, BIAS2, fin, D, HD);
    launch_transpose(P.qw, WT3, fin, HD, s);
    launch_mfma(xu, WT1, BIAS1, KRb, N_NODES, HD, fin, 0, s);            // kr_u
    launch_mfma(xu, WT2, BIAS2, VRb, N_NODES, HD, fin, 0, s);            // vr_u
    launch_mfma(xa, WT3, P.qb, B5, N_NODES, HD, fin, 0, s);              // q_a
    edge_fused_kernel<D><<<N_NODES, 256, 0, s>>>(
        B5, KRb, VRb, ua.rp, ua.src, ua.eid, ea_ua,
        P.prel + NH, P.ew + NH, P.eb + NH, B7, scale);                   // B7 = gelu(agg_a)

    // ---- per-type output linear (gelu applied in edge kernel), elu-out
    launch_transpose(P.alw, WT1, HD, HD, s);
    launch_mfma(B7, WT1, P.alb, ya, N_NODES, HD, HD, 1, s);              // out_a
    launch_transpose(P.alw + (size_t)HD * HD, WT2, HD, HD, s);
    launch_mfma(B6, WT2, P.alb + HD, yu, N_NODES, HD, HD, 1, s);         // out_u
}

extern "C" void kernel_launch(void* const* d_in, const int* in_sizes, int n_in,
                              void* d_out, int out_size, void* d_ws, size_t ws_size,
                              hipStream_t stream)
{
    // ---- inputs
    const float* x_ant  = (const float*)d_in[0];
    const float* x_user = (const float*)d_in[1];
    const float* ea_au  = (const float*)d_in[2];
    const float* ea_ua  = (const float*)d_in[3];
    LayerParams L1 = {
        (const float*)d_in[4],  (const float*)d_in[5],  (const float*)d_in[6],
        (const float*)d_in[7],  (const float*)d_in[8],  (const float*)d_in[9],
        (const float*)d_in[10], (const float*)d_in[11], (const float*)d_in[12],
        (const float*)d_in[13], (const float*)d_in[14], (const float*)d_in[15],
        (const float*)d_in[16]
    };
    LayerParams L2 = {
        (const float*)d_in[17], (const float*)d_in[18], (const float*)d_in[19],
        (const float*)d_in[20], (const float*)d_in[21], (const float*)d_in[22],
        (const float*)d_in[23], (const float*)d_in[24], (const float*)d_in[25],
        (const float*)d_in[26], (const float*)d_in[27], (const float*)d_in[28],
        (const float*)d_in[29]
    };
    const float* lin1_w  = (const float*)d_in[30];
    const float* lin1_b  = (const float*)d_in[31];
    const float* bn_g    = (const float*)d_in[32];
    const float* bn_b    = (const float*)d_in[33];
    const float* lin2_wa = (const float*)d_in[34];
    const float* lin2_ba = (const float*)d_in[35];
    const float* lin2_wu = (const float*)d_in[36];
    const float* lin2_bu = (const float*)d_in[37];
    const int*   ei_au   = (const int*)d_in[38];
    const int*   ei_ua   = (const int*)d_in[39];

    // ---- workspace arena
    float* F = (float*)d_ws;
    const size_t SLOT = (size_t)N_NODES * 320;
    float* B0 = F + 0 * SLOT;
    float* B1 = F + 1 * SLOT;
    float* B2 = F + 2 * SLOT;
    float* B3 = F + 3 * SLOT;   // KR bf16 table lives here
    float* B4 = F + 4 * SLOT;   // VR bf16 table
    float* B5 = F + 5 * SLOT;   // Q f32
    float* B6 = F + 6 * SLOT;
    float* B7 = F + 7 * SLOT;
    float* STATS = F + 8 * SLOT;                        // 1024 f32
    const size_t WT_ELEMS = 512 * 320;                  // max transposed weight
    __hip_bfloat16* WT1 = (__hip_bfloat16*)(STATS + 1024);
    __hip_bfloat16* WT2 = WT1 + WT_ELEMS;
    __hip_bfloat16* WT3 = WT2 + WT_ELEMS;
    float* BIAS1 = (float*)(WT3 + WT_ELEMS);            // 512 f32
    float* BIAS2 = BIAS1 + 512;
    int* I = (int*)(BIAS2 + 512);
    int* rp_au  = I;
    int* rp_ua  = rp_au + N_NODES + 1;
    int* src_au = rp_ua + N_NODES + 1;
    int* eid_au = src_au + N_EDGES;
    int* src_ua = eid_au + N_EDGES;
    int* eid_ua = src_ua + N_EDGES;
    int* cursor = eid_ua + N_EDGES;
    int* counts = cursor + N_NODES;

    const int gE = (N_EDGES + 255) / 256;

    // ---- CSR build (per relation, reused by both layers)
    hipMemsetAsync(counts, 0, N_NODES * sizeof(int), stream);
    count_kernel<<<gE, 256, 0, stream>>>(ei_au, counts);
    exscan_kernel<<<1, 1024, 0, stream>>>(counts, rp_au, cursor, N_NODES);
    scatter_kernel<<<gE, 256, 0, stream>>>(ei_au, cursor, src_au, eid_au);

    hipMemsetAsync(counts, 0, N_NODES * sizeof(int), stream);
    count_kernel<<<gE, 256, 0, stream>>>(ei_ua, counts);
    exscan_kernel<<<1, 1024, 0, stream>>>(counts, rp_ua, cursor, N_NODES);
    scatter_kernel<<<gE, 256, 0, stream>>>(ei_ua, cursor, src_ua, eid_ua);

    CsrRel au = { rp_au, src_au, eid_au };
    CsrRel ua = { rp_ua, src_ua, eid_ua };

    __hip_bfloat16* KRb = (__hip_bfloat16*)B3;
    __hip_bfloat16* VRb = (__hip_bfloat16*)B4;

    // ---- HGT layer 1: fin=128, D=16 -> B0 (ant), B1 (user), elu applied
    run_layer<16>(L1, 128, x_ant, x_user, B5, B6, B7, KRb, VRb,
                  WT1, WT2, WT3, BIAS1, BIAS2, B0, B1,
                  ea_au, ea_ua, au, ua, stream);

    // ---- HGT layer 2: fin=160, D=32 -> B0, B1, elu applied
    run_layer<32>(L2, 160, B0, B1, B5, B6, B7, KRb, VRb,
                  WT1, WT2, WT3, BIAS1, BIAS2, B0, B1,
                  ea_au, ea_ua, au, ua, stream);

    // ---- lin1 + elu:  [N,320] @ [320,512]
    float* L1A = B2;   // spans B2..B3
    float* L1U = B4;   // spans B4..B5
    launch_transpose(lin1_w, WT1, 320, 512, stream);
    launch_transpose(lin1_w + (size_t)320 * 512, WT2, 320, 512, stream);
    launch_mfma(B0, WT1, lin1_b, L1A, N_NODES, 512, 320, 1, stream);
    launch_mfma(B1, WT2, lin1_b + 512, L1U, N_NODES, 512, 320, 1, stream);

    // ---- batchnorm (population stats over rows), in-place
    hipMemsetAsync(STATS, 0, 1024 * sizeof(float), stream);
    colstat_kernel<<<dim3(8, 32), 256, 0, stream>>>(L1A, STATS, N_NODES, 512);
    bn_kernel<<<(N_NODES * 512 + 255) / 256, 256, 0, stream>>>(L1A, STATS, bn_g, bn_b,
                                                               N_NODES, 512);
    hipMemsetAsync(STATS, 0, 1024 * sizeof(float), stream);
    colstat_kernel<<<dim3(8, 32), 256, 0, stream>>>(L1U, STATS, N_NODES, 512);
    bn_kernel<<<(N_NODES * 512 + 255) / 256, 256, 0, stream>>>(L1U, STATS, bn_g + 512,
                                                               bn_b + 512, N_NODES, 512);

    // ---- lin2 + output epilogues
    float* OUTA = B6;  // [N,128]
    float* OUTU = B7;  // [N,129]
    launch_transpose(lin2_wa, WT1, 512, 128, stream);
    launch_mfma(L1A, WT1, lin2_ba, OUTA, N_NODES, 128, 512, 0, stream);
    rownorm_kernel<<<N_NODES, 64, 0, stream>>>(OUTA, (float*)d_out);
    launch_transpose(lin2_wu, WT2, 512, 129, stream);
    launch_mfma(L1U, WT2, lin2_bu, OUTU, N_NODES, 129, 512, 0, stream);
    rowsoftmax_kernel<<<N_NODES, 64, 0, stream>>>(
        OUTU, (float*)d_out + (size_t)N_NODES * 128);
}

// Round 7
// 1177.714 us; speedup vs baseline: 9.1397x; 1.1726x over previous
//
#include <hip/hip_runtime.h>
#include <hip/hip_bf16.h>
#include <math.h>

#define N_NODES 20000
#define N_EDGES 400000
#define NH 10

typedef __attribute__((ext_vector_type(8))) short short8v;
typedef __attribute__((ext_vector_type(4))) float f32x4;

// ---------------------------------------------------------------- helpers
__device__ __forceinline__ float gelu_f(float x) {
    float x3 = x * x * x;
    return 0.5f * x * (1.0f + tanhf(0.7978845608028654f * (x + 0.044715f * x3)));
}
__device__ __forceinline__ float elu_f(float x) {
    return x > 0.0f ? x : (expf(x) - 1.0f);
}
__device__ __forceinline__ float bf_lo(unsigned int w) {
    return __uint_as_float(w << 16);
}
__device__ __forceinline__ float bf_hi(unsigned int w) {
    return __uint_as_float(w & 0xffff0000u);
}
__device__ __forceinline__ unsigned short f2b(float x) {   // RNE f32->bf16 bits
    unsigned int u = __float_as_uint(x);
    return (unsigned short)((u + 0x7fffu + ((u >> 16) & 1u)) >> 16);
}

// ---------------------------------------------------------------- MFMA GEMM (bf16 x bf16 -> OUT)
// C[M,N] = act(A[M,K] @ W[K,N] + bias[N]); A bf16 [M][K], W TRANSPOSED bf16 [N][K].
// BM=128, BN=64, BK=32; 256 thr = 4 waves, each 64x32 (4x2 16x16 frags).
// K multiple of 32. LDS pitch 40 bf16 (80B) -> conflict-free-ish ds_read_b128.
template<int ACT, typename OUT>
__global__ __launch_bounds__(256) void mfma_gemm_kernel(
    const __hip_bfloat16* __restrict__ A, const __hip_bfloat16* __restrict__ WT,
    const float* __restrict__ bias, OUT* __restrict__ C,
    int M, int N, int K)
{
    constexpr int PITCH = 40;
    __shared__ __align__(16) unsigned short As[128 * PITCH];
    __shared__ __align__(16) unsigned short Bs[64 * PITCH];
    const int tid = threadIdx.x;
    const int m0 = blockIdx.y * 128, n0 = blockIdx.x * 64;
    const int w = tid >> 6, l = tid & 63;
    const int wr = w >> 1, wc = w & 1;
    const int lr = l & 15, lk = l >> 4;

    const int arow = tid >> 1, aseg = (tid & 1) * 16;   // 2 thr/row, 16 elems each
    const int brow = tid >> 2, bseg = (tid & 3) * 8;    // 4 thr/row, 8 elems each
    const bool ainb = (m0 + arow) < M;
    const bool binb = (n0 + brow) < N;

    f32x4 acc[4][2] = {};
    for (int k0 = 0; k0 < K; k0 += 32) {
        // stage A tile (pure bf16 copy, 32B/thread)
        {
            const __hip_bfloat16* ap = A + (size_t)(m0 + arow) * K + k0 + aseg;
            int4 v0 = ainb ? *reinterpret_cast<const int4*>(ap) : make_int4(0, 0, 0, 0);
            int4 v1 = ainb ? *reinterpret_cast<const int4*>(ap + 8) : make_int4(0, 0, 0, 0);
            *reinterpret_cast<int4*>(&As[arow * PITCH + aseg]) = v0;
            *reinterpret_cast<int4*>(&As[arow * PITCH + aseg + 8]) = v1;
        }
        // stage B tile (16B/thread)
        {
            int4 v = binb ? *reinterpret_cast<const int4*>(
                                WT + (size_t)(n0 + brow) * K + k0 + bseg)
                          : make_int4(0, 0, 0, 0);
            *reinterpret_cast<int4*>(&Bs[brow * PITCH + bseg]) = v;
        }
        __syncthreads();
        short8v a[4], b[2];
        #pragma unroll
        for (int mi = 0; mi < 4; ++mi)
            a[mi] = *reinterpret_cast<const short8v*>(
                &As[(wr * 64 + mi * 16 + lr) * PITCH + lk * 8]);
        #pragma unroll
        for (int ni = 0; ni < 2; ++ni)
            b[ni] = *reinterpret_cast<const short8v*>(
                &Bs[(wc * 32 + ni * 16 + lr) * PITCH + lk * 8]);
        #pragma unroll
        for (int mi = 0; mi < 4; ++mi)
            #pragma unroll
            for (int ni = 0; ni < 2; ++ni)
                acc[mi][ni] = __builtin_amdgcn_mfma_f32_16x16x32_bf16(
                    a[mi], b[ni], acc[mi][ni], 0, 0, 0);
        __syncthreads();
    }
    // epilogue: col=lane&15, row=(lane>>4)*4+reg (m89-verified)
    #pragma unroll
    for (int ni = 0; ni < 2; ++ni) {
        const int col = n0 + wc * 32 + ni * 16 + lr;
        if (col >= N) continue;
        const float bv = bias[col];
        #pragma unroll
        for (int mi = 0; mi < 4; ++mi) {
            const int rb = m0 + wr * 64 + mi * 16 + lk * 4;
            #pragma unroll
            for (int j = 0; j < 4; ++j) {
                const int m = rb + j;
                if (m >= M) continue;
                float v = acc[mi][ni][j] + bv;
                if (ACT == 1) v = elu_f(v);
                if constexpr (sizeof(OUT) == 2)
                    C[(size_t)m * N + col] = __float2bfloat16(v);
                else
                    C[(size_t)m * N + col] = v;
            }
        }
    }
}

// ---------------------------------------------------------------- small utility kernels
// f32 [K][N] -> bf16 [N][K]
__global__ void transpose_w_kernel(const float* __restrict__ in,
                                   __hip_bfloat16* __restrict__ out, int K, int N)
{
    __shared__ float tile[32][33];
    const int nb = blockIdx.x * 32, kb = blockIdx.y * 32;
    const int tx = threadIdx.x & 31, ty = threadIdx.x >> 5;
    for (int j = ty; j < 32; j += 8) {
        int k = kb + j, n = nb + tx;
        tile[j][tx] = (k < K && n < N) ? in[(size_t)k * N + n] : 0.f;
    }
    __syncthreads();
    for (int j = ty; j < 32; j += 8) {
        int n = nb + j, k = kb + tx;
        if (n < N && k < K) out[(size_t)n * K + k] = __float2bfloat16(tile[tx][j]);
    }
}

__global__ void f32_to_bf16_kernel(const float* __restrict__ in,
                                   __hip_bfloat16* __restrict__ out, int n4)
{
    int i = blockIdx.x * blockDim.x + threadIdx.x;
    if (i >= n4) return;
    float4 v = reinterpret_cast<const float4*>(in)[i];
    ushort4 b;
    b.x = f2b(v.x); b.y = f2b(v.y); b.z = f2b(v.z); b.w = f2b(v.w);
    reinterpret_cast<ushort4*>(out)[i] = b;
}

__global__ void copyf_kernel(const float* __restrict__ in, float* __restrict__ out, int n)
{
    int i = blockIdx.x * blockDim.x + threadIdx.x;
    if (i < n) out[i] = in[i];
}

// fused K/V weight: WfT[col][f] = bf16(sum_d KW[f][h*D+d]*REL[h][d][e]); biasv[col] from kb
__global__ void fuse_w_kernel(const float* __restrict__ KW, const float* __restrict__ kb,
                              const float* __restrict__ REL,
                              __hip_bfloat16* __restrict__ WfT, float* __restrict__ biasv,
                              int fin, int D, int HD)
{
    const int total = (fin + 1) * HD;
    int tid = blockIdx.x * blockDim.x + threadIdx.x;
    if (tid >= total) return;
    const int col = tid % HD, f = tid / HD;
    const int h = col / D, e = col - h * D;
    const float* src = (f < fin) ? KW + (size_t)f * HD + h * D : kb + h * D;
    const float* r = REL + (size_t)h * D * D + e;
    float acc = 0.f;
    for (int d = 0; d < D; ++d) acc = fmaf(src[d], r[(size_t)d * D], acc);
    if (f < fin) WfT[(size_t)col * fin + f] = __float2bfloat16(acc);
    else         biasv[col] = acc;
}

// ---------------------------------------------------------------- fused edge pipeline (BOTH relations)
// grid = 2*N_NODES; rel = blockIdx&1 (0: ant->user, 1: user->ant), dst = blockIdx>>1.
// Node tables T*[N, 3HD] bf16 hold (q | kr | vr). Online chunked segment softmax.
template<int D>
__global__ __launch_bounds__(256) void edge_fused_kernel(
    const __hip_bfloat16* __restrict__ Ta, const __hip_bfloat16* __restrict__ Tu,
    const int* __restrict__ rp0, const int* __restrict__ src0, const int* __restrict__ eid0,
    const int* __restrict__ rp1, const int* __restrict__ src1, const int* __restrict__ eid1,
    const float* __restrict__ ea0, const float* __restrict__ ea1,
    const float* __restrict__ prel, const float* __restrict__ ew,
    const float* __restrict__ eb,                 // [2*NH]
    __hip_bfloat16* __restrict__ outA, __hip_bfloat16* __restrict__ outU,
    float scale)
{
    constexpr int HD = NH * D;
    constexpr int S = 3 * HD;
    constexpr int PAIRS = HD / 2;
    constexpr int C = 64;
    __shared__ float q_s[HD];
    __shared__ float ls[C][NH];
    __shared__ int   srcs[C];
    __shared__ float eas[C];
    __shared__ float prel_s[NH], ew_s[NH], eb_s[NH];
    __shared__ float m_s[NH], s_s[NH], rexp_s[NH];

    const int b = blockIdx.x;
    const int rel = b & 1, dst = b >> 1;
    const int t = threadIdx.x;
    const __hip_bfloat16* Tkv = rel ? Tu : Ta;
    const __hip_bfloat16* Tq  = rel ? Ta : Tu;
    const int* rp   = rel ? rp1 : rp0;
    const int* srcA = rel ? src1 : src0;
    const int* eidA = rel ? eid1 : eid0;
    const float* ea = rel ? ea1 : ea0;
    __hip_bfloat16* out = rel ? outA : outU;

    const int s0 = rp[dst], s1 = rp[dst + 1];
    const int deg = s1 - s0;

    // stage q row (bf16 -> f32)
    {
        const unsigned int* qrow = (const unsigned int*)(Tq + (size_t)dst * S);
        for (int i = t; i < HD / 2; i += 256) {
            unsigned int w = qrow[i];
            q_s[2 * i] = bf_lo(w);
            q_s[2 * i + 1] = bf_hi(w);
        }
    }
    if (t < NH) { prel_s[t] = prel[rel * NH + t]; ew_s[t] = ew[rel * NH + t];
                  eb_s[t] = eb[rel * NH + t];
                  m_s[t] = -3.4e38f;  s_s[t] = 0.f; }
    float2 acc = make_float2(0.f, 0.f);
    const int hp = (2 * t) / D;
    __syncthreads();

    for (int base = 0; base < deg; base += C) {
        const int cl = min(C, deg - base);
        if (t < cl) {
            srcs[t] = srcA[s0 + base + t];
            eas[t]  = ea[eidA[s0 + base + t]];
        }
        __syncthreads();
        // logits: item = p*NH + h
        for (int item = t; item < cl * NH; item += 256) {
            const int p = item / NH, h = item - p * NH;
            const unsigned int* kr =
                (const unsigned int*)(Tkv + (size_t)srcs[p] * S + HD + h * D);
            const float* q = q_s + h * D;
            float d0 = 0.f;
            #pragma unroll
            for (int dd = 0; dd < D / 2; ++dd) {
                const unsigned int w = kr[dd];
                d0 = fmaf(q[2 * dd],     bf_lo(w), d0);
                d0 = fmaf(q[2 * dd + 1], bf_hi(w), d0);
            }
            ls[p][h] = d0 * scale * prel_s[h] + eas[p] * ew_s[h] + eb_s[h];
        }
        __syncthreads();
        // per-head online softmax: 16 lanes/head
        if (t < NH * 16) {
            const int h = t >> 4, sub = t & 15;
            float cm = -3.4e38f;
            for (int p = sub; p < cl; p += 16) cm = fmaxf(cm, ls[p][h]);
            #pragma unroll
            for (int off = 8; off; off >>= 1) cm = fmaxf(cm, __shfl_xor(cm, off));
            const float nm = fmaxf(m_s[h], cm);
            float cs = 0.f;
            for (int p = sub; p < cl; p += 16) {
                float w = expf(ls[p][h] - nm);
                ls[p][h] = w;
                cs += w;
            }
            #pragma unroll
            for (int off = 8; off; off >>= 1) cs += __shfl_xor(cs, off);
            if (sub == 0) {
                const float r = expf(m_s[h] - nm);
                s_s[h] = s_s[h] * r + cs;
                m_s[h] = nm;
                rexp_s[h] = r;
            }
        }
        __syncthreads();
        // aggregate vr pairs
        if (t < PAIRS) {
            const float r = rexp_s[hp];
            acc.x *= r; acc.y *= r;
            for (int p = 0; p < cl; ++p) {
                const unsigned int w = *(const unsigned int*)(
                    Tkv + (size_t)srcs[p] * S + 2 * HD + 2 * t);
                const float wgt = ls[p][hp];
                acc.x = fmaf(wgt, bf_lo(w), acc.x);
                acc.y = fmaf(wgt, bf_hi(w), acc.y);
            }
        }
        __syncthreads();
    }
    if (t < PAIRS) {
        const float inv = 1.f / (s_s[hp] + 1e-16f);
        const unsigned int r = (unsigned int)f2b(gelu_f(acc.x * inv)) |
                               ((unsigned int)f2b(gelu_f(acc.y * inv)) << 16);
        ((unsigned int*)(out + (size_t)dst * HD))[t] = r;
    }
}

// ---------------------------------------------------------------- CSR build
__global__ void count_kernel(const int* __restrict__ ei, int* __restrict__ cnt)
{
    int e = blockIdx.x * blockDim.x + threadIdx.x;
    if (e < N_EDGES) atomicAdd(&cnt[ei[N_EDGES + e]], 1);
}

__global__ void scatter_kernel(const int* __restrict__ ei, int* __restrict__ cursor,
                               int* __restrict__ srcA, int* __restrict__ eidA)
{
    int e = blockIdx.x * blockDim.x + threadIdx.x;
    if (e >= N_EDGES) return;
    int dst = ei[N_EDGES + e];
    int pos = atomicAdd(&cursor[dst], 1);
    srcA[pos] = ei[e];
    eidA[pos] = e;
}

__global__ void exscan_kernel(const int* __restrict__ cnt, int* __restrict__ rp,
                              int* __restrict__ cursor, int n)
{
    __shared__ int buf[1024];
    __shared__ int carry;
    int t = threadIdx.x;
    if (t == 0) carry = 0;
    __syncthreads();
    for (int base = 0; base < n; base += 1024) {
        int v = (base + t < n) ? cnt[base + t] : 0;
        buf[t] = v;
        __syncthreads();
        for (int off = 1; off < 1024; off <<= 1) {
            int x = (t >= off) ? buf[t - off] : 0;
            __syncthreads();
            buf[t] += x;
            __syncthreads();
        }
        int excl = buf[t] - v + carry;
        if (base + t < n) { rp[base + t] = excl; cursor[base + t] = excl; }
        int total = buf[1023];
        __syncthreads();
        if (t == 0) carry += total;
        __syncthreads();
    }
    if (t == 0) rp[n] = carry;
}

// ---------------------------------------------------------------- batchnorm (bf16 tensor)
__global__ void colstat_kernel(const __hip_bfloat16* __restrict__ X, float* __restrict__ sums,
                               int M, int N)
{
    __shared__ float ls[256], lq[256];
    int c = blockIdx.x * 64 + (threadIdx.x & 63);
    int rl = threadIdx.x >> 6;
    float s = 0.f, q = 0.f;
    for (int r = blockIdx.y * 4 + rl; r < M; r += gridDim.y * 4) {
        float v = __bfloat162float(X[(size_t)r * N + c]);
        s += v; q = fmaf(v, v, q);
    }
    ls[threadIdx.x] = s; lq[threadIdx.x] = q;
    __syncthreads();
    if (rl == 0) {
        s = ls[threadIdx.x] + ls[threadIdx.x + 64] + ls[threadIdx.x + 128] + ls[threadIdx.x + 192];
        q = lq[threadIdx.x] + lq[threadIdx.x + 64] + lq[threadIdx.x + 128] + lq[threadIdx.x + 192];
        atomicAdd(&sums[c], s);
        atomicAdd(&sums[N + c], q);
    }
}

__global__ void bn_kernel(__hip_bfloat16* __restrict__ X, const float* __restrict__ sums,
                          const float* __restrict__ g, const float* __restrict__ b,
                          int M, int N)
{
    int tid = blockIdx.x * blockDim.x + threadIdx.x;
    if (tid >= M * N) return;
    int c = tid % N;
    float mu = sums[c] / (float)M;
    float var = sums[N + c] / (float)M - mu * mu;
    float x = __bfloat162float(X[tid]);
    X[tid] = __float2bfloat16((x - mu) * rsqrtf(var + 1e-5f) * g[c] + b[c]);
}

// ---------------------------------------------------------------- output epilogues
__global__ void rownorm_kernel(const float* __restrict__ X, float* __restrict__ out)
{
    int row = blockIdx.x;
    int l = threadIdx.x;
    const float* x = X + (size_t)row * 128;
    float v0 = x[l], v1 = x[l + 64];
    float ss = v0 * v0 + v1 * v1;
    #pragma unroll
    for (int off = 32; off; off >>= 1) ss += __shfl_xor(ss, off);
    float inv = rsqrtf(ss + 1e-12f);
    out[(size_t)row * 128 + l] = v0 * inv;
    out[(size_t)row * 128 + l + 64] = v1 * inv;
}

__global__ void rowsoftmax_kernel(const float* __restrict__ X, float* __restrict__ out)
{
    int row = blockIdx.x;
    int l = threadIdx.x;
    const float* x = X + (size_t)row * 129;
    float v0 = x[l], v1 = x[l + 64];
    float v2 = (l == 0) ? x[128] : -3.4e38f;
    float m = fmaxf(fmaxf(v0, v1), v2);
    #pragma unroll
    for (int off = 32; off; off >>= 1) m = fmaxf(m, __shfl_xor(m, off));
    float e0 = expf(v0 - m), e1 = expf(v1 - m);
    float e2 = (l == 0) ? expf(v2 - m) : 0.f;
    float s = e0 + e1 + e2;
    #pragma unroll
    for (int off = 32; off; off >>= 1) s += __shfl_xor(s, off);
    float inv = 1.f / s;
    out[(size_t)row * 129 + l] = e0 * inv;
    out[(size_t)row * 129 + l + 64] = e1 * inv;
    if (l == 0) out[(size_t)row * 129 + 128] = e2 * inv;
}

// ---------------------------------------------------------------- host-side plumbing
template<typename OUT>
static inline void launch_mfma(const __hip_bfloat16* A, const __hip_bfloat16* WT,
                               const float* bias, OUT* C,
                               int M, int N, int K, int act, hipStream_t s)
{
    dim3 grid((N + 63) / 64, (M + 127) / 128);
    if (act) mfma_gemm_kernel<1, OUT><<<grid, 256, 0, s>>>(A, WT, bias, C, M, N, K);
    else     mfma_gemm_kernel<0, OUT><<<grid, 256, 0, s>>>(A, WT, bias, C, M, N, K);
}
static inline void launch_transpose(const float* in, __hip_bfloat16* out,
                                    int K, int N, hipStream_t s)
{
    dim3 grid((N + 31) / 32, (K + 31) / 32);
    transpose_w_kernel<<<grid, 256, 0, s>>>(in, out, K, N);
}

struct LayerParams {
    const float *kw, *kb, *qw, *qb, *vw, *vb, *arel, *mrel, *prel, *ew, *eb, *alw, *alb;
};

struct CsrRel { const int* rp; const int* src; const int* eid; };

// builds cat (q|k|v) weights+bias for one node type and runs the table GEMM
template<int D>
static void build_type_table(const LayerParams& P, int fin, int type,
                             const __hip_bfloat16* x, __hip_bfloat16* T,
                             __hip_bfloat16* WT, float* BIAS, hipStream_t s)
{
    const int HD = NH * D;
    const int gFW = ((fin + 1) * HD + 255) / 256;
    const size_t woff = (size_t)type * fin * HD;
    // q rows [0,HD)
    launch_transpose(P.qw + woff, WT, fin, HD, s);
    copyf_kernel<<<(HD + 255) / 256, 256, 0, s>>>(P.qb + type * HD, BIAS, HD);
    // k rows [HD,2HD), v rows [2HD,3HD)
    fuse_w_kernel<<<gFW, 256, 0, s>>>(P.kw + woff, P.kb + type * HD,
                                      P.arel + (size_t)type * NH * D * D,
                                      WT + (size_t)HD * fin, BIAS + HD, fin, D, HD);
    fuse_w_kernel<<<gFW, 256, 0, s>>>(P.vw + woff, P.vb + type * HD,
                                      P.mrel + (size_t)type * NH * D * D,
                                      WT + (size_t)2 * HD * fin, BIAS + 2 * HD, fin, D, HD);
    launch_mfma(x, WT, BIAS, T, N_NODES, 3 * HD, fin, 0, s);
}

template<int D>
static void run_layer(const LayerParams& P, int fin,
                      const __hip_bfloat16* xa, const __hip_bfloat16* xu,
                      __hip_bfloat16* TA, __hip_bfloat16* TU,
                      __hip_bfloat16* AGA, __hip_bfloat16* AGU,
                      __hip_bfloat16* ya, __hip_bfloat16* yu,
                      __hip_bfloat16* WT1, __hip_bfloat16* WT2,
                      float* BIAS1, float* BIAS2,
                      const float* ea_au, const float* ea_ua,
                      const CsrRel& au, const CsrRel& ua, hipStream_t s)
{
    const int HD = NH * D;
    const float scale = 1.0f / sqrtf((float)D);

    build_type_table<D>(P, fin, 0, xa, TA, WT1, BIAS1, s);   // ant: q_a|kr_a|vr_a
    build_type_table<D>(P, fin, 1, xu, TU, WT2, BIAS2, s);   // user: q_u|kr_u|vr_u

    edge_fused_kernel<D><<<2 * N_NODES, 256, 0, s>>>(
        TA, TU, au.rp, au.src, au.eid, ua.rp, ua.src, ua.eid,
        ea_au, ea_ua, P.prel, P.ew, P.eb, AGA, AGU, scale);

    // per-type output linear (gelu applied in edge kernel), elu-out
    launch_transpose(P.alw, WT1, HD, HD, s);
    launch_mfma(AGA, WT1, P.alb, ya, N_NODES, HD, HD, 1, s);
    launch_transpose(P.alw + (size_t)HD * HD, WT2, HD, HD, s);
    launch_mfma(AGU, WT2, P.alb + HD, yu, N_NODES, HD, HD, 1, s);
}

extern "C" void kernel_launch(void* const* d_in, const int* in_sizes, int n_in,
                              void* d_out, int out_size, void* d_ws, size_t ws_size,
                              hipStream_t stream)
{
    // ---- inputs
    const float* x_ant  = (const float*)d_in[0];
    const float* x_user = (const float*)d_in[1];
    const float* ea_au  = (const float*)d_in[2];
    const float* ea_ua  = (const float*)d_in[3];
    LayerParams L1 = {
        (const float*)d_in[4],  (const float*)d_in[5],  (const float*)d_in[6],
        (const float*)d_in[7],  (const float*)d_in[8],  (const float*)d_in[9],
        (const float*)d_in[10], (const float*)d_in[11], (const float*)d_in[12],
        (const float*)d_in[13], (const float*)d_in[14], (const float*)d_in[15],
        (const float*)d_in[16]
    };
    LayerParams L2 = {
        (const float*)d_in[17], (const float*)d_in[18], (const float*)d_in[19],
        (const float*)d_in[20], (const float*)d_in[21], (const float*)d_in[22],
        (const float*)d_in[23], (const float*)d_in[24], (const float*)d_in[25],
        (const float*)d_in[26], (const float*)d_in[27], (const float*)d_in[28],
        (const float*)d_in[29]
    };
    const float* lin1_w  = (const float*)d_in[30];
    const float* lin1_b  = (const float*)d_in[31];
    const float* bn_g    = (const float*)d_in[32];
    const float* bn_b    = (const float*)d_in[33];
    const float* lin2_wa = (const float*)d_in[34];
    const float* lin2_ba = (const float*)d_in[35];
    const float* lin2_wu = (const float*)d_in[36];
    const float* lin2_bu = (const float*)d_in[37];
    const int*   ei_au   = (const int*)d_in[38];
    const int*   ei_ua   = (const int*)d_in[39];

    // ---- workspace arena (byte carve, 256B aligned)
    char* P8 = (char*)d_ws;
    auto carve = [&](size_t bytes) { char* p = P8; P8 += (bytes + 255) & ~(size_t)255; return p; };
    __hip_bfloat16* XA  = (__hip_bfloat16*)carve((size_t)N_NODES * 128 * 2);
    __hip_bfloat16* XU  = (__hip_bfloat16*)carve((size_t)N_NODES * 128 * 2);
    __hip_bfloat16* TA  = (__hip_bfloat16*)carve((size_t)N_NODES * 960 * 2);
    __hip_bfloat16* TU  = (__hip_bfloat16*)carve((size_t)N_NODES * 960 * 2);
    __hip_bfloat16* AGA = (__hip_bfloat16*)carve((size_t)N_NODES * 320 * 2);
    __hip_bfloat16* AGU = (__hip_bfloat16*)carve((size_t)N_NODES * 320 * 2);
    __hip_bfloat16* YA  = (__hip_bfloat16*)carve((size_t)N_NODES * 320 * 2);
    __hip_bfloat16* YU  = (__hip_bfloat16*)carve((size_t)N_NODES * 320 * 2);
    __hip_bfloat16* L1A = (__hip_bfloat16*)carve((size_t)N_NODES * 512 * 2);
    __hip_bfloat16* L1U = (__hip_bfloat16*)carve((size_t)N_NODES * 512 * 2);
    __hip_bfloat16* WT1 = (__hip_bfloat16*)carve(960 * 320 * 2);
    __hip_bfloat16* WT2 = (__hip_bfloat16*)carve(960 * 320 * 2);
    float* BIAS1 = (float*)carve(960 * 4);
    float* BIAS2 = (float*)carve(960 * 4);
    float* STATS = (float*)carve(1024 * 4);
    int* rp_au  = (int*)carve((N_NODES + 1) * 4);
    int* rp_ua  = (int*)carve((N_NODES + 1) * 4);
    int* src_au = (int*)carve((size_t)N_EDGES * 4);
    int* eid_au = (int*)carve((size_t)N_EDGES * 4);
    int* src_ua = (int*)carve((size_t)N_EDGES * 4);
    int* eid_ua = (int*)carve((size_t)N_EDGES * 4);
    int* cursor = (int*)carve(N_NODES * 4);
    int* counts = (int*)carve(N_NODES * 4);

    const int gE = (N_EDGES + 255) / 256;

    // ---- CSR build (per relation, reused by both layers)
    hipMemsetAsync(counts, 0, N_NODES * sizeof(int), stream);
    count_kernel<<<gE, 256, 0, stream>>>(ei_au, counts);
    exscan_kernel<<<1, 1024, 0, stream>>>(counts, rp_au, cursor, N_NODES);
    scatter_kernel<<<gE, 256, 0, stream>>>(ei_au, cursor, src_au, eid_au);

    hipMemsetAsync(counts, 0, N_NODES * sizeof(int), stream);
    count_kernel<<<gE, 256, 0, stream>>>(ei_ua, counts);
    exscan_kernel<<<1, 1024, 0, stream>>>(counts, rp_ua, cursor, N_NODES);
    scatter_kernel<<<gE, 256, 0, stream>>>(ei_ua, cursor, src_ua, eid_ua);

    CsrRel au = { rp_au, src_au, eid_au };
    CsrRel ua = { rp_ua, src_ua, eid_ua };

    // ---- input f32 -> bf16
    f32_to_bf16_kernel<<<(N_NODES * 128 / 4 + 255) / 256, 256, 0, stream>>>(
        x_ant, XA, N_NODES * 128 / 4);
    f32_to_bf16_kernel<<<(N_NODES * 128 / 4 + 255) / 256, 256, 0, stream>>>(
        x_user, XU, N_NODES * 128 / 4);

    // ---- HGT layer 1: fin=128, D=16 -> YA/YU [N,160] bf16 (elu applied)
    run_layer<16>(L1, 128, XA, XU, TA, TU, AGA, AGU, YA, YU,
                  WT1, WT2, BIAS1, BIAS2, ea_au, ea_ua, au, ua, stream);

    // ---- HGT layer 2: fin=160, D=32 -> outputs into TA/TU (table space dead after edge)
    run_layer<32>(L2, 160, YA, YU, TA, TU, AGA, AGU, TA, TU,
                  WT1, WT2, BIAS1, BIAS2, ea_au, ea_ua, au, ua, stream);

    // ---- lin1 + elu: [N,320] @ [320,512] -> bf16
    launch_transpose(lin1_w, WT1, 320, 512, stream);
    launch_mfma(TA, WT1, lin1_b, L1A, N_NODES, 512, 320, 1, stream);
    launch_transpose(lin1_w + (size_t)320 * 512, WT2, 320, 512, stream);
    launch_mfma(TU, WT2, lin1_b + 512, L1U, N_NODES, 512, 320, 1, stream);

    // ---- batchnorm (population stats), in-place on bf16
    hipMemsetAsync(STATS, 0, 1024 * sizeof(float), stream);
    colstat_kernel<<<dim3(8, 32), 256, 0, stream>>>(L1A, STATS, N_NODES, 512);
    bn_kernel<<<(N_NODES * 512 + 255) / 256, 256, 0, stream>>>(L1A, STATS, bn_g, bn_b,
                                                               N_NODES, 512);
    hipMemsetAsync(STATS, 0, 1024 * sizeof(float), stream);
    colstat_kernel<<<dim3(8, 32), 256, 0, stream>>>(L1U, STATS, N_NODES, 512);
    bn_kernel<<<(N_NODES * 512 + 255) / 256, 256, 0, stream>>>(L1U, STATS, bn_g + 512,
                                                               bn_b + 512, N_NODES, 512);

    // ---- lin2 (f32 out) + epilogues; OUT buffers reuse AGA/AGU space
    float* OUTA = (float*)AGA;   // [N,128] f32 (10.24MB <= 12.8MB)
    float* OUTU = (float*)AGU;   // [N,129] f32
    launch_transpose(lin2_wa, WT1, 512, 128, stream);
    launch_mfma(L1A, WT1, lin2_ba, OUTA, N_NODES, 128, 512, 0, stream);
    rownorm_kernel<<<N_NODES, 64, 0, stream>>>(OUTA, (float*)d_out);
    launch_transpose(lin2_wu, WT2, 512, 129, stream);
    launch_mfma(L1U, WT2, lin2_bu, OUTU, N_NODES, 129, 512, 0, stream);
    rowsoftmax_kernel<<<N_NODES, 64, 0, stream>>>(
        OUTU, (float*)d_out + (size_t)N_NODES * 128);
}